// Round 8
// baseline (540.252 us; speedup 1.0000x reference)
//
#include <hip/hip_runtime.h>
#include <cstdint>
#include <cstddef>

#define AS1 __attribute__((address_space(1)))
#define AS3 __attribute__((address_space(3)))

typedef __attribute__((ext_vector_type(8))) __bf16 bf16x8;
typedef __attribute__((ext_vector_type(4))) float f32x4;

__device__ __forceinline__ void gload_lds16(const void* g, void* l) {
  __builtin_amdgcn_global_load_lds((AS1 void*)g, (AS3 void*)l, 16, 0, 0);
}

// ---------------- weight transpose f32 -> bf16 : dst[N][ldd] slice = src[K][N]^T ----------------
__global__ void k_transpose_w(const float* __restrict__ src, __bf16* __restrict__ dst,
                              int K, int N, int ldd, int koff) {
  __shared__ float tile[32][33];
  const int bx = blockIdx.x * 32;  // N dim
  const int by = blockIdx.y * 32;  // K dim
  const int tx = threadIdx.x, ty = threadIdx.y;
#pragma unroll
  for (int ii = 0; ii < 4; ++ii) {
    int i = ty + ii * 8;
    tile[i][tx] = src[(size_t)(by + i) * N + bx + tx];
  }
  __syncthreads();
#pragma unroll
  for (int ii = 0; ii < 4; ++ii) {
    int i = ty + ii * 8;
    dst[(size_t)(bx + i) * ldd + koff + by + tx] = (__bf16)tile[tx][i];
  }
}

// ---------------- pack qkv bias ----------------
__global__ void k_pack_bias(const float* __restrict__ bq, const float* __restrict__ bk,
                            const float* __restrict__ bv, float* __restrict__ dst) {
  int i = blockIdx.x * 256 + threadIdx.x;
  if (i < 768) dst[i] = bq[i];
  else if (i < 1536) dst[i] = bk[i - 768];
  else if (i < 2304) dst[i] = bv[i - 1536];
}

// ---------------- LayerNorm f32 -> bf16 (one wave per 768-row) ----------------
__global__ __launch_bounds__(256) void k_layernorm(const float* __restrict__ x,
                                                   const float* __restrict__ g,
                                                   const float* __restrict__ b,
                                                   __bf16* __restrict__ out) {
  const int row = blockIdx.x * 4 + (threadIdx.x >> 6);
  const int lane = threadIdx.x & 63;
  const float* xr = x + (size_t)row * 768;
  float4 v[3];
#pragma unroll
  for (int j = 0; j < 3; ++j) v[j] = *(const float4*)(xr + j * 256 + lane * 4);
  float s = 0.f, ss = 0.f;
#pragma unroll
  for (int j = 0; j < 3; ++j) {
    s += v[j].x + v[j].y + v[j].z + v[j].w;
    ss += v[j].x * v[j].x + v[j].y * v[j].y + v[j].z * v[j].z + v[j].w * v[j].w;
  }
#pragma unroll
  for (int off = 32; off > 0; off >>= 1) {
    s += __shfl_xor(s, off);
    ss += __shfl_xor(ss, off);
  }
  const float mu = s * (1.f / 768.f);
  const float rstd = rsqrtf(ss * (1.f / 768.f) - mu * mu + 1e-5f);
  __bf16* orow = out + (size_t)row * 768;
#pragma unroll
  for (int j = 0; j < 3; ++j) {
    float4 gg = *(const float4*)(g + j * 256 + lane * 4);
    float4 bb = *(const float4*)(b + j * 256 + lane * 4);
    const int base = j * 256 + lane * 4;
    orow[base + 0] = (__bf16)((v[j].x - mu) * rstd * gg.x + bb.x);
    orow[base + 1] = (__bf16)((v[j].y - mu) * rstd * gg.y + bb.y);
    orow[base + 2] = (__bf16)((v[j].z - mu) * rstd * gg.z + bb.z);
    orow[base + 3] = (__bf16)((v[j].w - mu) * rstd * gg.w + bb.w);
  }
}

// ---------------- GEMM: C[M][N] = A[M][K] * BT[N][K]^T + bias (+epilogue) ----------------
// MODE 0: store bf16; cols<768 (Q) pre-scaled by log2(e) so attn can use exp2
// MODE 1: + resid, store f32
// MODE 2: tanh-approx GELU, store bf16
template <int MODE>
__global__ __launch_bounds__(256) void k_gemm(const __bf16* __restrict__ A,
                                              const __bf16* __restrict__ BT,
                                              const float* __restrict__ bias,
                                              const float* __restrict__ resid,
                                              void* __restrict__ Cout,
                                              int M, int N, int K) {
  __shared__ __bf16 As[128 * 32];
  __shared__ __bf16 Bs[128 * 32];
  const int m0 = blockIdx.y * 128, n0 = blockIdx.x * 128;
  const int tid = threadIdx.x;
  const int wid = tid >> 6, lane = tid & 63;
  const int wm = wid >> 1, wn = wid & 1;
  const int lr = lane & 15, lg = lane >> 4;

  f32x4 acc[4][4] = {};

  for (int k0 = 0; k0 < K; k0 += 32) {
#pragma unroll
    for (int it = 0; it < 2; ++it) {
      int t = tid + it * 256;
      int r = t >> 2, c = (t & 3) * 8;
      gload_lds16(A + (size_t)(m0 + r) * K + k0 + c, As + t * 8);
      gload_lds16(BT + (size_t)(n0 + r) * K + k0 + c, Bs + t * 8);
    }
    __syncthreads();
    bf16x8 af[4], bf[4];
#pragma unroll
    for (int i = 0; i < 4; ++i) af[i] = *(const bf16x8*)(As + (wm * 64 + i * 16 + lr) * 32 + lg * 8);
#pragma unroll
    for (int j = 0; j < 4; ++j) bf[j] = *(const bf16x8*)(Bs + (wn * 64 + j * 16 + lr) * 32 + lg * 8);
#pragma unroll
    for (int i = 0; i < 4; ++i)
#pragma unroll
      for (int j = 0; j < 4; ++j)
        acc[i][j] = __builtin_amdgcn_mfma_f32_16x16x32_bf16(af[i], bf[j], acc[i][j], 0, 0, 0);
    __syncthreads();
  }

#pragma unroll
  for (int i = 0; i < 4; ++i)
#pragma unroll
    for (int j = 0; j < 4; ++j)
#pragma unroll
      for (int r = 0; r < 4; ++r) {
        int row = m0 + wm * 64 + i * 16 + lg * 4 + r;
        int col = n0 + wn * 64 + j * 16 + lr;
        float v = acc[i][j][r] + bias[col];
        size_t idx = (size_t)row * N + col;
        if constexpr (MODE == 0) {
          if (col < 768) v *= 1.44269504088896f;  // Q pre-scale: exp(x) = exp2(x*log2e)
          ((__bf16*)Cout)[idx] = (__bf16)v;
        } else if constexpr (MODE == 1) {
          ((float*)Cout)[idx] = v + resid[idx];
        } else {
          // tanh-approx GELU (error ~3e-4, far under threshold)
          float u = 0.7978845608f * (v + 0.044715f * v * v * v);
          float t = exp2f(u * 2.88539008f);  // e^{2u}
          float th = 1.f - 2.f * __builtin_amdgcn_rcpf(t + 1.f);
          ((__bf16*)Cout)[idx] = (__bf16)(0.5f * v * (1.f + th));
        }
      }
}

// ---------------- pack K into fragment-major KA16 (plain rows, 16-k granules) ----------------
// KA16[b][kb16][hp][hh][dc][lane][8] = K[b][kb*16 + (lane&15)][hp*192+hh*96+dc*32+(lane>>4)*8 + e]
__global__ __launch_bounds__(256) void k_pack_ka(const __bf16* __restrict__ qkv,
                                                 __bf16* __restrict__ KA) {
  const int kb = blockIdx.x, b = blockIdx.y;  // kb in [0,256)
  const int t = threadIdx.x;
#pragma unroll
  for (int i = 0; i < 6; ++i) {
    int c = t + i * 256;  // [0,1536)
    int lane = c & 63, f = c >> 6;  // f in [0,24)
    int dc = f % 3, hh = (f / 3) & 1, hp = f / 6;
    int row = kb * 16 + (lane & 15);
    int col = 768 + hp * 192 + hh * 96 + dc * 32 + (lane >> 4) * 8;
    bf16x8 v = *(const bf16x8*)(qkv + (size_t)(b * 4096 + row) * 2304 + col);
    *(bf16x8*)(KA + ((size_t)(b * 256 + kb) * 1536 + c) * 8) = v;
  }
}

// ---------------- pack V, kappa-permuted, fragment-major VA32 (32-k granules) ----------------
// VA32[b][g][hp][hh][db][lane][e] = V[b][g*32 + kappa][hp*192+hh*96+db*16+(lane&15)]
// kappa(lg,e) = (e>>2)*16 + lg*4 + (e&3)  -- matches P-register slot order of two 16-k QK tiles.
__global__ __launch_bounds__(256) void k_pack_va(const __bf16* __restrict__ qkv,
                                                 __bf16* __restrict__ VA) {
  __shared__ __bf16 vtile[32][772];
  const int g = blockIdx.x, b = blockIdx.y;  // g in [0,128)
  const int t = threadIdx.x;
#pragma unroll
  for (int i = 0; i < 12; ++i) {
    int c = t + i * 256;
    int row = c / 96, c8 = c % 96;
    *(bf16x8*)(&vtile[row][c8 * 8]) =
        *(const bf16x8*)(qkv + (size_t)(b * 4096 + g * 32 + row) * 2304 + 1536 + c8 * 8);
  }
  __syncthreads();
#pragma unroll
  for (int i = 0; i < 12; ++i) {
    int c = t + i * 256;  // [0,3072)
    int lane = c & 63, f = c >> 6;  // f in [0,48)
    int db = f % 6, hh = (f / 6) & 1, hp = f / 12;
    int d = hp * 192 + hh * 96 + db * 16 + (lane & 15);
    int lg_ = lane >> 4;
    bf16x8 v;
#pragma unroll
    for (int e = 0; e < 8; ++e) {
      int krow = (e >> 2) * 16 + lg_ * 4 + (e & 3);
      v[e] = vtile[krow][d];
    }
    *(bf16x8*)(VA + ((size_t)(b * 128 + g) * 3072 + c) * 8) = v;
  }
}

// ---------------- fused attention v8: LDS-shared K/V + counted-vmcnt prefetch ----------------
// grid 512: slice = bid&7 -> (b,ks) per-XCD; qb = bid>>3 -> 64 q-rows.
// 16 waves = (qs 0..3) x (hp 0..3). 64 rounds of 16 k. K double-buffered; V single 32k
// buffer staged at even rounds. Stage order K-then-V; even barriers use vmcnt(3) so V's
// 3 loads stay in flight until the odd barrier's vmcnt(0) (full extra half-round cover).
// Q pre-scaled by log2e in QKV epilogue -> exp2f here.
__global__ __launch_bounds__(1024, 4) void k_attn(const __bf16* __restrict__ qkv,
                                                  const __bf16* __restrict__ KA,
                                                  const __bf16* __restrict__ VA,
                                                  __bf16* __restrict__ attn4) {
  __shared__ __bf16 Kb_s[2][12288];   // 2 x 24.6 KB (16k x 4hp)
  __shared__ __bf16 Vb_s[24576];      // 49.2 KB (32k x 4hp)
  __shared__ float ps_s[2][4352];     // 2 x [4qs][16kslot][4hp][17]
  const int bid = blockIdx.x;
  const int slice = bid & 7;
  const int b = slice >> 2, ks = slice & 3;
  const int qb = bid >> 3;
  const int wid = threadIdx.x >> 6;
  const int qs = wid & 3, hp = wid >> 2;
  const int q0 = qb * 64 + qs * 16;
  const int lane = threadIdx.x & 63;
  const int lr = lane & 15, lg = lane >> 4;

  // Q fragments (one-time 16-row gather, reused 64 rounds)
  const __bf16* Qb = qkv + (size_t)(b * 4096 + q0) * 2304;
  bf16x8 qf[2][3];
#pragma unroll
  for (int hh = 0; hh < 2; ++hh)
#pragma unroll
    for (int dc = 0; dc < 3; ++dc)
      qf[hh][dc] = *(const bf16x8*)(Qb + (size_t)lr * 2304 + (hp * 2 + hh) * 96 + dc * 32 + lg * 8);

  // staging work split: K = 24 x 1KB loads (waves 0..7 take 2, 8..15 take 1); V = 48, 3 per wave
  const int L1 = wid, hpK1 = L1 / 6, jK1 = L1 - hpK1 * 6;
  const int L2 = wid + 16, hpK2 = L2 / 6, jK2 = L2 - hpK2 * 6;

  int kb = ks * 64;
  // prologue: stage K(kb0) into buffer 0
  {
    const __bf16* srcK = KA + (size_t)(b * 256 + kb) * 12288;
    gload_lds16(srcK + hpK1 * 3072 + jK1 * 512 + lane * 8,
                &Kb_s[0][hpK1 * 3072 + jK1 * 512 + lane * 8]);
    if (wid < 8)
      gload_lds16(srcK + hpK2 * 3072 + jK2 * 512 + lane * 8,
                  &Kb_s[0][hpK2 * 3072 + jK2 * 512 + lane * 8]);
  }
  asm volatile("s_waitcnt vmcnt(0)" ::: "memory");
  __builtin_amdgcn_s_barrier();
  asm volatile("" ::: "memory");

  f32x4 o[2][6] = {};
  f32x4 eA[2], eB[2];  // [hh] energy tiles for the two 16-k halves of a 32-k group

#define HALF(ET, PAR, DO_V, DO_PV) do {                                               \
    { /* stage K(kb+1) FIRST (drained at this round's barrier) */                     \
      size_t kidx = (size_t)(b * 256 + kb + 1);                                       \
      if (kidx > 511) kidx = 511;                                                     \
      const __bf16* srcK = KA + kidx * 12288;                                         \
      gload_lds16(srcK + hpK1 * 3072 + jK1 * 512 + lane * 8,                          \
                  &Kb_s[PAR ^ 1][hpK1 * 3072 + jK1 * 512 + lane * 8]);                \
      if (wid < 8)                                                                    \
        gload_lds16(srcK + hpK2 * 3072 + jK2 * 512 + lane * 8,                        \
                    &Kb_s[PAR ^ 1][hpK2 * 3072 + jK2 * 512 + lane * 8]);              \
    }                                                                                 \
    if (DO_V) { /* stage V second: stays in flight until the NEXT (odd) barrier */    \
      const __bf16* srcV = VA + (size_t)(b * 128 + (kb >> 1)) * 24576;                \
      _Pragma("unroll")                                                               \
      for (int tt = 0; tt < 3; ++tt) {                                                \
        int L = wid * 3 + tt;                                                         \
        int hpV = L / 12, jV = L - hpV * 12;                                          \
        gload_lds16(srcV + hpV * 6144 + jV * 512 + lane * 8,                          \
                    &Vb_s[hpV * 6144 + jV * 512 + lane * 8]);                         \
      }                                                                               \
    }                                                                                 \
    /* QK^T from LDS */                                                               \
    ET[0] = (f32x4){0.f, 0.f, 0.f, 0.f};                                              \
    ET[1] = (f32x4){0.f, 0.f, 0.f, 0.f};                                              \
    {                                                                                 \
      const __bf16* kbase = &Kb_s[PAR][hp * 3072 + lane * 8];                         \
      __builtin_amdgcn_s_setprio(1);                                                  \
      _Pragma("unroll")                                                               \
      for (int hh = 0; hh < 2; ++hh)                                                  \
        _Pragma("unroll")                                                             \
        for (int dc = 0; dc < 3; ++dc) {                                              \
          bf16x8 kf = *(const bf16x8*)(kbase + (hh * 3 + dc) * 512);                  \
          ET[hh] = __builtin_amdgcn_mfma_f32_16x16x32_bf16(kf, qf[hh][dc], ET[hh],    \
                                                           0, 0, 0);                  \
        }                                                                             \
      __builtin_amdgcn_s_setprio(0);                                                  \
    }                                                                                 \
    /* exp2 (Q pre-scaled) + 2-head partial sums -> psum[PAR] */                      \
    _Pragma("unroll")                                                                 \
    for (int rr = 0; rr < 4; ++rr) {                                                  \
      float e0 = exp2f(ET[0][rr]);                                                    \
      float e1 = exp2f(ET[1][rr]);                                                    \
      ET[0][rr] = e0;                                                                 \
      ET[1][rr] = e1;                                                                 \
      ps_s[PAR][qs * 1088 + (lg * 4 + rr) * 68 + hp * 17 + lr] = e0 + e1;             \
    }                                                                                 \
    if (DO_V) {                                                                       \
      asm volatile("s_waitcnt vmcnt(3) lgkmcnt(0)" ::: "memory");                     \
    } else {                                                                          \
      asm volatile("s_waitcnt vmcnt(0) lgkmcnt(0)" ::: "memory");                     \
    }                                                                                 \
    __builtin_amdgcn_s_barrier();                                                     \
    asm volatile("" ::: "memory");                                                    \
    /* denominator exchange + normalize in-register */                                \
    {                                                                                 \
      float inv_[4];                                                                  \
      _Pragma("unroll")                                                               \
      for (int rr = 0; rr < 4; ++rr) {                                                \
        const int base = qs * 1088 + (lg * 4 + rr) * 68 + lr;                         \
        float tot = (ps_s[PAR][base] + ps_s[PAR][base + 17]) +                        \
                    (ps_s[PAR][base + 34] + ps_s[PAR][base + 51]);                    \
        inv_[rr] = 0.03608439182435161f * __builtin_amdgcn_rcpf(tot);                 \
      }                                                                               \
      _Pragma("unroll")                                                               \
      for (int rr = 0; rr < 4; ++rr) {                                                \
        ET[0][rr] *= inv_[rr];                                                        \
        ET[1][rr] *= inv_[rr];                                                        \
      }                                                                               \
    }                                                                                 \
    if (DO_PV) { /* PV over the 32-k group from eA,eB (kappa-matched VA) */           \
      bf16x8 pf0, pf1;                                                                \
      _Pragma("unroll")                                                               \
      for (int e2 = 0; e2 < 8; ++e2) {                                                \
        int rr = e2 & 3;                                                              \
        if (e2 < 4) { pf0[e2] = (__bf16)eA[0][rr]; pf1[e2] = (__bf16)eA[1][rr]; }     \
        else        { pf0[e2] = (__bf16)eB[0][rr]; pf1[e2] = (__bf16)eB[1][rr]; }     \
      }                                                                               \
      const __bf16* vbase = &Vb_s[hp * 6144 + lane * 8];                              \
      __builtin_amdgcn_s_setprio(1);                                                  \
      _Pragma("unroll")                                                               \
      for (int db = 0; db < 6; ++db) {                                                \
        bf16x8 vf0 = *(const bf16x8*)(vbase + db * 512);                              \
        bf16x8 vf1 = *(const bf16x8*)(vbase + (6 + db) * 512);                        \
        o[0][db] = __builtin_amdgcn_mfma_f32_16x16x32_bf16(pf0, vf0, o[0][db], 0, 0, 0); \
        o[1][db] = __builtin_amdgcn_mfma_f32_16x16x32_bf16(pf1, vf1, o[1][db], 0, 0, 0); \
      }                                                                               \
      __builtin_amdgcn_s_setprio(0);                                                  \
    }                                                                                 \
    ++kb;                                                                             \
  } while (0)

  for (int rp = 0; rp < 64; rp += 2) {
    HALF(eA, 0, 1, 0);  // even 16-k half: stages V(group), no PV
    HALF(eB, 1, 0, 1);  // odd half: PV over the full 32-k group
  }
#undef HALF

#pragma unroll
  for (int hh = 0; hh < 2; ++hh)
#pragma unroll
    for (int db = 0; db < 6; ++db)
#pragma unroll
      for (int rr = 0; rr < 4; ++rr)
        attn4[(size_t)(b * 4096 + q0 + lg * 4 + rr) * 3072 + ks * 768 +
              (hp * 2 + hh) * 96 + db * 16 + lr] = (__bf16)o[hh][db][rr];
}

// ---------------- reduce 4 k-split slices -> bf16 ----------------
__global__ __launch_bounds__(256) void k_reduce_attn(const __bf16* __restrict__ attn4,
                                                     __bf16* __restrict__ out) {
  int g = blockIdx.x * 256 + threadIdx.x;  // chunk of 8, total 8192*96
  int row = g / 96, c8 = g % 96;
  const __bf16* p = attn4 + (size_t)row * 3072 + c8 * 8;
  float acc[8] = {};
#pragma unroll
  for (int s = 0; s < 4; ++s) {
    bf16x8 v = *(const bf16x8*)(p + s * 768);
#pragma unroll
    for (int e = 0; e < 8; ++e) acc[e] += (float)v[e];
  }
  bf16x8 r;
#pragma unroll
  for (int e = 0; e < 8; ++e) r[e] = (__bf16)acc[e];
  *(bf16x8*)(out + (size_t)row * 768 + c8 * 8) = r;
}

// ---------------- launcher ----------------
extern "C" void kernel_launch(void* const* d_in, const int* in_sizes, int n_in,
                              void* d_out, int out_size, void* d_ws, size_t ws_size,
                              hipStream_t stream) {
  (void)in_sizes; (void)n_in; (void)out_size; (void)ws_size;
  const float* x     = (const float*)d_in[0];
  const float* ln1_g = (const float*)d_in[1];
  const float* ln1_b = (const float*)d_in[2];
  const float* wq    = (const float*)d_in[3];
  const float* bq    = (const float*)d_in[4];
  const float* wk    = (const float*)d_in[5];
  const float* bk    = (const float*)d_in[6];
  const float* wv    = (const float*)d_in[7];
  const float* bv    = (const float*)d_in[8];
  const float* wp    = (const float*)d_in[9];
  const float* bp    = (const float*)d_in[10];
  const float* ln2_g = (const float*)d_in[11];
  const float* ln2_b = (const float*)d_in[12];
  const float* w1    = (const float*)d_in[13];
  const float* b1    = (const float*)d_in[14];
  const float* w2    = (const float*)d_in[15];
  const float* b2    = (const float*)d_in[16];

  char* ws = (char*)d_ws;
  const size_t o_wqkvT = 0;                                   // [2304][768] bf16
  const size_t o_wpT   = o_wqkvT + (size_t)2304 * 768 * 2;    // [768][768] bf16
  const size_t o_w1T   = o_wpT   + (size_t)768 * 768 * 2;     // [3072][768] bf16
  const size_t o_w2T   = o_w1T   + (size_t)768 * 3072 * 2;    // [768][3072] bf16
  const size_t o_bqkv  = o_w2T   + (size_t)3072 * 768 * 2;    // [2304] f32
  const size_t o_xn    = o_bqkv  + (size_t)2304 * 4;          // [8192][768] bf16
  const size_t o_qkv   = o_xn    + (size_t)8192 * 768 * 2;    // [8192][2304] bf16
  const size_t o_KA    = o_qkv   + (size_t)8192 * 2304 * 2;   // [2][256][1536][8] bf16
  const size_t o_VA    = o_KA    + (size_t)2 * 256 * 1536 * 8 * 2;
  const size_t o_attn4 = o_VA    + (size_t)2 * 128 * 3072 * 8 * 2;  // [8192][3072] bf16
  // aliases (lifetime-disjoint):
  const size_t o_x1      = o_attn4;  // [8192][768] f32 (written after attn4 last read)
  const size_t o_attnred = o_KA;     // [8192][768] bf16 (KA dead after attention)
  const size_t o_xn2     = o_VA;     // [8192][768] bf16 (VA dead after attention)
  const size_t o_hmid    = o_xn;     // [8192][3072] bf16 (spans xn+qkv, both dead)

  __bf16* wqkvT = (__bf16*)(ws + o_wqkvT);
  __bf16* wpT   = (__bf16*)(ws + o_wpT);
  __bf16* w1T   = (__bf16*)(ws + o_w1T);
  __bf16* w2T   = (__bf16*)(ws + o_w2T);
  float*  bqkv  = (float*)(ws + o_bqkv);
  __bf16* xn    = (__bf16*)(ws + o_xn);
  __bf16* qkvb  = (__bf16*)(ws + o_qkv);
  __bf16* KA    = (__bf16*)(ws + o_KA);
  __bf16* VA    = (__bf16*)(ws + o_VA);
  __bf16* attn4 = (__bf16*)(ws + o_attn4);
  float*  x1    = (float*)(ws + o_x1);
  __bf16* attnr = (__bf16*)(ws + o_attnred);
  __bf16* xn2   = (__bf16*)(ws + o_xn2);
  __bf16* hmid  = (__bf16*)(ws + o_hmid);

  dim3 tb(32, 8);
  k_transpose_w<<<dim3(24, 24), tb, 0, stream>>>(wq, wqkvT, 768, 768, 768, 0);
  k_transpose_w<<<dim3(24, 24), tb, 0, stream>>>(wk, wqkvT + (size_t)768 * 768, 768, 768, 768, 0);
  k_transpose_w<<<dim3(24, 24), tb, 0, stream>>>(wv, wqkvT + (size_t)2 * 768 * 768, 768, 768, 768, 0);
  k_transpose_w<<<dim3(24, 24), tb, 0, stream>>>(wp, wpT, 768, 768, 768, 0);
  k_transpose_w<<<dim3(96, 24), tb, 0, stream>>>(w1, w1T, 768, 3072, 768, 0);
  k_transpose_w<<<dim3(24, 96), tb, 0, stream>>>(w2, w2T, 3072, 768, 3072, 0);
  k_pack_bias<<<9, 256, 0, stream>>>(bq, bk, bv, bqkv);

  // LN1 -> xn
  k_layernorm<<<2048, 256, 0, stream>>>(x, ln1_g, ln1_b, xn);
  // QKV projection (fused q|k|v; Q cols pre-scaled by log2e)
  k_gemm<0><<<dim3(18, 64), 256, 0, stream>>>(xn, wqkvT, bqkv, nullptr, qkvb, 8192, 2304, 768);
  // pack K (plain 16k frags) and V (kappa-permuted 32k frags)
  k_pack_ka<<<dim3(256, 2), 256, 0, stream>>>(qkvb, KA);
  k_pack_va<<<dim3(128, 2), 256, 0, stream>>>(qkvb, VA);
  // attention: 512 blocks x 16 waves, 133 KB LDS, slice pinned per XCD via bid&7
  k_attn<<<512, 1024, 0, stream>>>(qkvb, KA, VA, attn4);
  // sum 4 k-split slices
  k_reduce_attn<<<3072, 256, 0, stream>>>(attn4, attnr);
  // output projection + residual -> x1 (f32)
  k_gemm<1><<<dim3(6, 64), 256, 0, stream>>>(attnr, wpT, bp, x, x1, 8192, 768, 768);
  // LN2 -> xn2
  k_layernorm<<<2048, 256, 0, stream>>>(x1, ln2_g, ln2_b, xn2);
  // MLP1 + tanh-GELU -> hmid
  k_gemm<2><<<dim3(24, 64), 256, 0, stream>>>(xn2, w1T, b1, nullptr, hmid, 8192, 3072, 768);
  // MLP2 + residual -> out (f32)
  k_gemm<1><<<dim3(6, 64), 256, 0, stream>>>(hmid, w2T, b2, x1, (float*)d_out, 8192, 768, 3072);
}

// Round 9
// 497.414 us; speedup vs baseline: 1.0861x; 1.0861x over previous
//
#include <hip/hip_runtime.h>
#include <cstdint>
#include <cstddef>

#define AS1 __attribute__((address_space(1)))
#define AS3 __attribute__((address_space(3)))

typedef __attribute__((ext_vector_type(8))) __bf16 bf16x8;
typedef __attribute__((ext_vector_type(4))) float f32x4;

__device__ __forceinline__ void gload_lds16(const void* g, void* l) {
  __builtin_amdgcn_global_load_lds((AS1 void*)g, (AS3 void*)l, 16, 0, 0);
}

// ---------------- weight transpose f32 -> bf16 : dst[N][ldd] slice = src[K][N]^T ----------------
__global__ void k_transpose_w(const float* __restrict__ src, __bf16* __restrict__ dst,
                              int K, int N, int ldd, int koff) {
  __shared__ float tile[32][33];
  const int bx = blockIdx.x * 32;  // N dim
  const int by = blockIdx.y * 32;  // K dim
  const int tx = threadIdx.x, ty = threadIdx.y;
#pragma unroll
  for (int ii = 0; ii < 4; ++ii) {
    int i = ty + ii * 8;
    tile[i][tx] = src[(size_t)(by + i) * N + bx + tx];
  }
  __syncthreads();
#pragma unroll
  for (int ii = 0; ii < 4; ++ii) {
    int i = ty + ii * 8;
    dst[(size_t)(bx + i) * ldd + koff + by + tx] = (__bf16)tile[tx][i];
  }
}

// ---------------- pack qkv bias ----------------
__global__ void k_pack_bias(const float* __restrict__ bq, const float* __restrict__ bk,
                            const float* __restrict__ bv, float* __restrict__ dst) {
  int i = blockIdx.x * 256 + threadIdx.x;
  if (i < 768) dst[i] = bq[i];
  else if (i < 1536) dst[i] = bk[i - 768];
  else if (i < 2304) dst[i] = bv[i - 1536];
}

// ---------------- LayerNorm f32 -> bf16 (one wave per 768-row) ----------------
__global__ __launch_bounds__(256) void k_layernorm(const float* __restrict__ x,
                                                   const float* __restrict__ g,
                                                   const float* __restrict__ b,
                                                   __bf16* __restrict__ out) {
  const int row = blockIdx.x * 4 + (threadIdx.x >> 6);
  const int lane = threadIdx.x & 63;
  const float* xr = x + (size_t)row * 768;
  float4 v[3];
#pragma unroll
  for (int j = 0; j < 3; ++j) v[j] = *(const float4*)(xr + j * 256 + lane * 4);
  float s = 0.f, ss = 0.f;
#pragma unroll
  for (int j = 0; j < 3; ++j) {
    s += v[j].x + v[j].y + v[j].z + v[j].w;
    ss += v[j].x * v[j].x + v[j].y * v[j].y + v[j].z * v[j].z + v[j].w * v[j].w;
  }
#pragma unroll
  for (int off = 32; off > 0; off >>= 1) {
    s += __shfl_xor(s, off);
    ss += __shfl_xor(ss, off);
  }
  const float mu = s * (1.f / 768.f);
  const float rstd = rsqrtf(ss * (1.f / 768.f) - mu * mu + 1e-5f);
  __bf16* orow = out + (size_t)row * 768;
#pragma unroll
  for (int j = 0; j < 3; ++j) {
    float4 gg = *(const float4*)(g + j * 256 + lane * 4);
    float4 bb = *(const float4*)(b + j * 256 + lane * 4);
    const int base = j * 256 + lane * 4;
    orow[base + 0] = (__bf16)((v[j].x - mu) * rstd * gg.x + bb.x);
    orow[base + 1] = (__bf16)((v[j].y - mu) * rstd * gg.y + bb.y);
    orow[base + 2] = (__bf16)((v[j].z - mu) * rstd * gg.z + bb.z);
    orow[base + 3] = (__bf16)((v[j].w - mu) * rstd * gg.w + bb.w);
  }
}

// ---------------- GEMM: C[M][N] = A[M][K] * BT[N][K]^T + bias (+epilogue) ----------------
// MODE 0: store bf16; cols<768 (Q) pre-scaled by log2(e) so attn can use raw v_exp_f32
// MODE 1: + resid, store f32
// MODE 2: tanh-approx GELU (raw v_exp_f32), store bf16
template <int MODE>
__global__ __launch_bounds__(256) void k_gemm(const __bf16* __restrict__ A,
                                              const __bf16* __restrict__ BT,
                                              const float* __restrict__ bias,
                                              const float* __restrict__ resid,
                                              void* __restrict__ Cout,
                                              int M, int N, int K) {
  __shared__ __bf16 As[128 * 32];
  __shared__ __bf16 Bs[128 * 32];
  const int m0 = blockIdx.y * 128, n0 = blockIdx.x * 128;
  const int tid = threadIdx.x;
  const int wid = tid >> 6, lane = tid & 63;
  const int wm = wid >> 1, wn = wid & 1;
  const int lr = lane & 15, lg = lane >> 4;

  f32x4 acc[4][4] = {};

  for (int k0 = 0; k0 < K; k0 += 32) {
#pragma unroll
    for (int it = 0; it < 2; ++it) {
      int t = tid + it * 256;
      int r = t >> 2, c = (t & 3) * 8;
      gload_lds16(A + (size_t)(m0 + r) * K + k0 + c, As + t * 8);
      gload_lds16(BT + (size_t)(n0 + r) * K + k0 + c, Bs + t * 8);
    }
    __syncthreads();
    bf16x8 af[4], bf[4];
#pragma unroll
    for (int i = 0; i < 4; ++i) af[i] = *(const bf16x8*)(As + (wm * 64 + i * 16 + lr) * 32 + lg * 8);
#pragma unroll
    for (int j = 0; j < 4; ++j) bf[j] = *(const bf16x8*)(Bs + (wn * 64 + j * 16 + lr) * 32 + lg * 8);
#pragma unroll
    for (int i = 0; i < 4; ++i)
#pragma unroll
      for (int j = 0; j < 4; ++j)
        acc[i][j] = __builtin_amdgcn_mfma_f32_16x16x32_bf16(af[i], bf[j], acc[i][j], 0, 0, 0);
    __syncthreads();
  }

#pragma unroll
  for (int i = 0; i < 4; ++i)
#pragma unroll
    for (int j = 0; j < 4; ++j)
#pragma unroll
      for (int r = 0; r < 4; ++r) {
        int row = m0 + wm * 64 + i * 16 + lg * 4 + r;
        int col = n0 + wn * 64 + j * 16 + lr;
        float v = acc[i][j][r] + bias[col];
        size_t idx = (size_t)row * N + col;
        if constexpr (MODE == 0) {
          if (col < 768) v *= 1.44269504088896f;  // Q pre-scale: exp(x) = 2^(x*log2e)
          ((__bf16*)Cout)[idx] = (__bf16)v;
        } else if constexpr (MODE == 1) {
          ((float*)Cout)[idx] = v + resid[idx];
        } else {
          // tanh-approx GELU via raw v_exp_f32 (error ~3e-4, far under threshold)
          float u = 0.7978845608f * (v + 0.044715f * v * v * v);
          float t = __builtin_amdgcn_exp2f(u * 2.88539008f);  // e^{2u}
          float th = 1.f - 2.f * __builtin_amdgcn_rcpf(t + 1.f);
          ((__bf16*)Cout)[idx] = (__bf16)(0.5f * v * (1.f + th));
        }
      }
}

// ---------------- pack K into fragment-major KA16 (plain rows, 16-k granules) ----------------
// KA16[b][kb16][hp][hh][dc][lane][8] = K[b][kb*16 + (lane&15)][hp*192+hh*96+dc*32+(lane>>4)*8 + e]
__global__ __launch_bounds__(256) void k_pack_ka(const __bf16* __restrict__ qkv,
                                                 __bf16* __restrict__ KA) {
  const int kb = blockIdx.x, b = blockIdx.y;  // kb in [0,256)
  const int t = threadIdx.x;
#pragma unroll
  for (int i = 0; i < 6; ++i) {
    int c = t + i * 256;  // [0,1536)
    int lane = c & 63, f = c >> 6;  // f in [0,24)
    int dc = f % 3, hh = (f / 3) & 1, hp = f / 6;
    int row = kb * 16 + (lane & 15);
    int col = 768 + hp * 192 + hh * 96 + dc * 32 + (lane >> 4) * 8;
    bf16x8 v = *(const bf16x8*)(qkv + (size_t)(b * 4096 + row) * 2304 + col);
    *(bf16x8*)(KA + ((size_t)(b * 256 + kb) * 1536 + c) * 8) = v;
  }
}

// ---------------- pack V, kappa-permuted, fragment-major VA32 (32-k granules) ----------------
// VA32[b][g][hp][hh][db][lane][e] = V[b][g*32 + kappa][hp*192+hh*96+db*16+(lane&15)]
// kappa(lg,e) = (e>>2)*16 + lg*4 + (e&3)  -- matches P-register slot order of two 16-k QK tiles.
__global__ __launch_bounds__(256) void k_pack_va(const __bf16* __restrict__ qkv,
                                                 __bf16* __restrict__ VA) {
  __shared__ __bf16 vtile[32][772];
  const int g = blockIdx.x, b = blockIdx.y;  // g in [0,128)
  const int t = threadIdx.x;
#pragma unroll
  for (int i = 0; i < 12; ++i) {
    int c = t + i * 256;
    int row = c / 96, c8 = c % 96;
    *(bf16x8*)(&vtile[row][c8 * 8]) =
        *(const bf16x8*)(qkv + (size_t)(b * 4096 + g * 32 + row) * 2304 + 1536 + c8 * 8);
  }
  __syncthreads();
#pragma unroll
  for (int i = 0; i < 12; ++i) {
    int c = t + i * 256;  // [0,3072)
    int lane = c & 63, f = c >> 6;  // f in [0,48)
    int db = f % 6, hh = (f / 6) & 1, hp = f / 12;
    int d = hp * 192 + hh * 96 + db * 16 + (lane & 15);
    int lg_ = lane >> 4;
    bf16x8 v;
#pragma unroll
    for (int e = 0; e < 8; ++e) {
      int krow = (e >> 2) * 16 + lg_ * 4 + (e & 3);
      v[e] = vtile[krow][d];
    }
    *(bf16x8*)(VA + ((size_t)(b * 128 + g) * 3072 + c) * 8) = v;
  }
}

// ---------------- fused attention v9: v8 structure + raw v_exp_f32 ----------------
// grid 512: slice = bid&7 -> (b,ks) per-XCD; qb = bid>>3 -> 64 q-rows.
// 16 waves = (qs 0..3) x (hp 0..3). 64 rounds of 16 k. K double-buffered; V single 32k
// buffer staged at even rounds. Stage order K-then-V; even barriers use vmcnt(3) so V's
// 3 loads stay in flight until the odd barrier's vmcnt(0).
// Q pre-scaled by log2e in QKV epilogue -> raw __builtin_amdgcn_exp2f here.
__global__ __launch_bounds__(1024, 4) void k_attn(const __bf16* __restrict__ qkv,
                                                  const __bf16* __restrict__ KA,
                                                  const __bf16* __restrict__ VA,
                                                  __bf16* __restrict__ attn4) {
  __shared__ __bf16 Kb_s[2][12288];   // 2 x 24.6 KB (16k x 4hp)
  __shared__ __bf16 Vb_s[24576];      // 49.2 KB (32k x 4hp)
  __shared__ float ps_s[2][4352];     // 2 x [4qs][16kslot][4hp][17]
  const int bid = blockIdx.x;
  const int slice = bid & 7;
  const int b = slice >> 2, ks = slice & 3;
  const int qb = bid >> 3;
  const int wid = threadIdx.x >> 6;
  const int qs = wid & 3, hp = wid >> 2;
  const int q0 = qb * 64 + qs * 16;
  const int lane = threadIdx.x & 63;
  const int lr = lane & 15, lg = lane >> 4;

  // Q fragments (one-time 16-row gather, reused 64 rounds)
  const __bf16* Qb = qkv + (size_t)(b * 4096 + q0) * 2304;
  bf16x8 qf[2][3];
#pragma unroll
  for (int hh = 0; hh < 2; ++hh)
#pragma unroll
    for (int dc = 0; dc < 3; ++dc)
      qf[hh][dc] = *(const bf16x8*)(Qb + (size_t)lr * 2304 + (hp * 2 + hh) * 96 + dc * 32 + lg * 8);

  // staging work split: K = 24 x 1KB loads (waves 0..7 take 2, 8..15 take 1); V = 48, 3 per wave
  const int L1 = wid, hpK1 = L1 / 6, jK1 = L1 - hpK1 * 6;
  const int L2 = wid + 16, hpK2 = L2 / 6, jK2 = L2 - hpK2 * 6;

  int kb = ks * 64;
  // prologue: stage K(kb0) into buffer 0
  {
    const __bf16* srcK = KA + (size_t)(b * 256 + kb) * 12288;
    gload_lds16(srcK + hpK1 * 3072 + jK1 * 512 + lane * 8,
                &Kb_s[0][hpK1 * 3072 + jK1 * 512 + lane * 8]);
    if (wid < 8)
      gload_lds16(srcK + hpK2 * 3072 + jK2 * 512 + lane * 8,
                  &Kb_s[0][hpK2 * 3072 + jK2 * 512 + lane * 8]);
  }
  asm volatile("s_waitcnt vmcnt(0)" ::: "memory");
  __builtin_amdgcn_s_barrier();
  asm volatile("" ::: "memory");

  f32x4 o[2][6] = {};
  f32x4 eA[2], eB[2];  // [hh] energy tiles for the two 16-k halves of a 32-k group

#define HALF(ET, PAR, DO_V, DO_PV) do {                                               \
    { /* stage K(kb+1) FIRST (drained at this round's barrier) */                     \
      size_t kidx = (size_t)(b * 256 + kb + 1);                                       \
      if (kidx > 511) kidx = 511;                                                     \
      const __bf16* srcK = KA + kidx * 12288;                                         \
      gload_lds16(srcK + hpK1 * 3072 + jK1 * 512 + lane * 8,                          \
                  &Kb_s[PAR ^ 1][hpK1 * 3072 + jK1 * 512 + lane * 8]);                \
      if (wid < 8)                                                                    \
        gload_lds16(srcK + hpK2 * 3072 + jK2 * 512 + lane * 8,                        \
                    &Kb_s[PAR ^ 1][hpK2 * 3072 + jK2 * 512 + lane * 8]);              \
    }                                                                                 \
    if (DO_V) { /* stage V second: stays in flight until the NEXT (odd) barrier */    \
      const __bf16* srcV = VA + (size_t)(b * 128 + (kb >> 1)) * 24576;                \
      _Pragma("unroll")                                                               \
      for (int tt = 0; tt < 3; ++tt) {                                                \
        int L = wid * 3 + tt;                                                         \
        int hpV = L / 12, jV = L - hpV * 12;                                          \
        gload_lds16(srcV + hpV * 6144 + jV * 512 + lane * 8,                          \
                    &Vb_s[hpV * 6144 + jV * 512 + lane * 8]);                         \
      }                                                                               \
    }                                                                                 \
    /* QK^T from LDS */                                                               \
    ET[0] = (f32x4){0.f, 0.f, 0.f, 0.f};                                              \
    ET[1] = (f32x4){0.f, 0.f, 0.f, 0.f};                                              \
    {                                                                                 \
      const __bf16* kbase = &Kb_s[PAR][hp * 3072 + lane * 8];                         \
      __builtin_amdgcn_s_setprio(1);                                                  \
      _Pragma("unroll")                                                               \
      for (int hh = 0; hh < 2; ++hh)                                                  \
        _Pragma("unroll")                                                             \
        for (int dc = 0; dc < 3; ++dc) {                                              \
          bf16x8 kf = *(const bf16x8*)(kbase + (hh * 3 + dc) * 512);                  \
          ET[hh] = __builtin_amdgcn_mfma_f32_16x16x32_bf16(kf, qf[hh][dc], ET[hh],    \
                                                           0, 0, 0);                  \
        }                                                                             \
      __builtin_amdgcn_s_setprio(0);                                                  \
    }                                                                                 \
    /* raw 2^x (Q pre-scaled by log2e) + 2-head partial sums -> psum[PAR] */          \
    _Pragma("unroll")                                                                 \
    for (int rr = 0; rr < 4; ++rr) {                                                  \
      float e0 = __builtin_amdgcn_exp2f(ET[0][rr]);                                   \
      float e1 = __builtin_amdgcn_exp2f(ET[1][rr]);                                   \
      ET[0][rr] = e0;                                                                 \
      ET[1][rr] = e1;                                                                 \
      ps_s[PAR][qs * 1088 + (lg * 4 + rr) * 68 + hp * 17 + lr] = e0 + e1;             \
    }                                                                                 \
    if (DO_V) {                                                                       \
      asm volatile("s_waitcnt vmcnt(3) lgkmcnt(0)" ::: "memory");                     \
    } else {                                                                          \
      asm volatile("s_waitcnt vmcnt(0) lgkmcnt(0)" ::: "memory");                     \
    }                                                                                 \
    __builtin_amdgcn_s_barrier();                                                     \
    asm volatile("" ::: "memory");                                                    \
    /* denominator exchange + normalize in-register */                                \
    {                                                                                 \
      float inv_[4];                                                                  \
      _Pragma("unroll")                                                               \
      for (int rr = 0; rr < 4; ++rr) {                                                \
        const int base = qs * 1088 + (lg * 4 + rr) * 68 + lr;                         \
        float tot = (ps_s[PAR][base] + ps_s[PAR][base + 17]) +                        \
                    (ps_s[PAR][base + 34] + ps_s[PAR][base + 51]);                    \
        inv_[rr] = 0.03608439182435161f * __builtin_amdgcn_rcpf(tot);                 \
      }                                                                               \
      _Pragma("unroll")                                                               \
      for (int rr = 0; rr < 4; ++rr) {                                                \
        ET[0][rr] *= inv_[rr];                                                        \
        ET[1][rr] *= inv_[rr];                                                        \
      }                                                                               \
    }                                                                                 \
    if (DO_PV) { /* PV over the 32-k group from eA,eB (kappa-matched VA) */           \
      bf16x8 pf0, pf1;                                                                \
      _Pragma("unroll")                                                               \
      for (int e2 = 0; e2 < 8; ++e2) {                                                \
        int rr = e2 & 3;                                                              \
        if (e2 < 4) { pf0[e2] = (__bf16)eA[0][rr]; pf1[e2] = (__bf16)eA[1][rr]; }     \
        else        { pf0[e2] = (__bf16)eB[0][rr]; pf1[e2] = (__bf16)eB[1][rr]; }     \
      }                                                                               \
      const __bf16* vbase = &Vb_s[hp * 6144 + lane * 8];                              \
      __builtin_amdgcn_s_setprio(1);                                                  \
      _Pragma("unroll")                                                               \
      for (int db = 0; db < 6; ++db) {                                                \
        bf16x8 vf0 = *(const bf16x8*)(vbase + db * 512);                              \
        bf16x8 vf1 = *(const bf16x8*)(vbase + (6 + db) * 512);                        \
        o[0][db] = __builtin_amdgcn_mfma_f32_16x16x32_bf16(pf0, vf0, o[0][db], 0, 0, 0); \
        o[1][db] = __builtin_amdgcn_mfma_f32_16x16x32_bf16(pf1, vf1, o[1][db], 0, 0, 0); \
      }                                                                               \
      __builtin_amdgcn_s_setprio(0);                                                  \
    }                                                                                 \
    ++kb;                                                                             \
  } while (0)

  for (int rp = 0; rp < 64; rp += 2) {
    HALF(eA, 0, 1, 0);  // even 16-k half: stages V(group), no PV
    HALF(eB, 1, 0, 1);  // odd half: PV over the full 32-k group
  }
#undef HALF

#pragma unroll
  for (int hh = 0; hh < 2; ++hh)
#pragma unroll
    for (int db = 0; db < 6; ++db)
#pragma unroll
      for (int rr = 0; rr < 4; ++rr)
        attn4[(size_t)(b * 4096 + q0 + lg * 4 + rr) * 3072 + ks * 768 +
              (hp * 2 + hh) * 96 + db * 16 + lr] = (__bf16)o[hh][db][rr];
}

// ---------------- reduce 4 k-split slices -> bf16 ----------------
__global__ __launch_bounds__(256) void k_reduce_attn(const __bf16* __restrict__ attn4,
                                                     __bf16* __restrict__ out) {
  int g = blockIdx.x * 256 + threadIdx.x;  // chunk of 8, total 8192*96
  int row = g / 96, c8 = g % 96;
  const __bf16* p = attn4 + (size_t)row * 3072 + c8 * 8;
  float acc[8] = {};
#pragma unroll
  for (int s = 0; s < 4; ++s) {
    bf16x8 v = *(const bf16x8*)(p + s * 768);
#pragma unroll
    for (int e = 0; e < 8; ++e) acc[e] += (float)v[e];
  }
  bf16x8 r;
#pragma unroll
  for (int e = 0; e < 8; ++e) r[e] = (__bf16)acc[e];
  *(bf16x8*)(out + (size_t)row * 768 + c8 * 8) = r;
}

// ---------------- launcher ----------------
extern "C" void kernel_launch(void* const* d_in, const int* in_sizes, int n_in,
                              void* d_out, int out_size, void* d_ws, size_t ws_size,
                              hipStream_t stream) {
  (void)in_sizes; (void)n_in; (void)out_size; (void)ws_size;
  const float* x     = (const float*)d_in[0];
  const float* ln1_g = (const float*)d_in[1];
  const float* ln1_b = (const float*)d_in[2];
  const float* wq    = (const float*)d_in[3];
  const float* bq    = (const float*)d_in[4];
  const float* wk    = (const float*)d_in[5];
  const float* bk    = (const float*)d_in[6];
  const float* wv    = (const float*)d_in[7];
  const float* bv    = (const float*)d_in[8];
  const float* wp    = (const float*)d_in[9];
  const float* bp    = (const float*)d_in[10];
  const float* ln2_g = (const float*)d_in[11];
  const float* ln2_b = (const float*)d_in[12];
  const float* w1    = (const float*)d_in[13];
  const float* b1    = (const float*)d_in[14];
  const float* w2    = (const float*)d_in[15];
  const float* b2    = (const float*)d_in[16];

  char* ws = (char*)d_ws;
  const size_t o_wqkvT = 0;                                   // [2304][768] bf16
  const size_t o_wpT   = o_wqkvT + (size_t)2304 * 768 * 2;    // [768][768] bf16
  const size_t o_w1T   = o_wpT   + (size_t)768 * 768 * 2;     // [3072][768] bf16
  const size_t o_w2T   = o_w1T   + (size_t)768 * 3072 * 2;    // [768][3072] bf16
  const size_t o_bqkv  = o_w2T   + (size_t)3072 * 768 * 2;    // [2304] f32
  const size_t o_xn    = o_bqkv  + (size_t)2304 * 4;          // [8192][768] bf16
  const size_t o_qkv   = o_xn    + (size_t)8192 * 768 * 2;    // [8192][2304] bf16
  const size_t o_KA    = o_qkv   + (size_t)8192 * 2304 * 2;   // [2][256][1536][8] bf16
  const size_t o_VA    = o_KA    + (size_t)2 * 256 * 1536 * 8 * 2;
  const size_t o_attn4 = o_VA    + (size_t)2 * 128 * 3072 * 8 * 2;  // [8192][3072] bf16
  // aliases (lifetime-disjoint):
  const size_t o_x1      = o_attn4;  // [8192][768] f32 (written after attn4 last read)
  const size_t o_attnred = o_KA;     // [8192][768] bf16 (KA dead after attention)
  const size_t o_xn2     = o_VA;     // [8192][768] bf16 (VA dead after attention)
  const size_t o_hmid    = o_xn;     // [8192][3072] bf16 (spans xn+qkv, both dead)

  __bf16* wqkvT = (__bf16*)(ws + o_wqkvT);
  __bf16* wpT   = (__bf16*)(ws + o_wpT);
  __bf16* w1T   = (__bf16*)(ws + o_w1T);
  __bf16* w2T   = (__bf16*)(ws + o_w2T);
  float*  bqkv  = (float*)(ws + o_bqkv);
  __bf16* xn    = (__bf16*)(ws + o_xn);
  __bf16* qkvb  = (__bf16*)(ws + o_qkv);
  __bf16* KA    = (__bf16*)(ws + o_KA);
  __bf16* VA    = (__bf16*)(ws + o_VA);
  __bf16* attn4 = (__bf16*)(ws + o_attn4);
  float*  x1    = (float*)(ws + o_x1);
  __bf16* attnr = (__bf16*)(ws + o_attnred);
  __bf16* xn2   = (__bf16*)(ws + o_xn2);
  __bf16* hmid  = (__bf16*)(ws + o_hmid);

  dim3 tb(32, 8);
  k_transpose_w<<<dim3(24, 24), tb, 0, stream>>>(wq, wqkvT, 768, 768, 768, 0);
  k_transpose_w<<<dim3(24, 24), tb, 0, stream>>>(wk, wqkvT + (size_t)768 * 768, 768, 768, 768, 0);
  k_transpose_w<<<dim3(24, 24), tb, 0, stream>>>(wv, wqkvT + (size_t)2 * 768 * 768, 768, 768, 768, 0);
  k_transpose_w<<<dim3(24, 24), tb, 0, stream>>>(wp, wpT, 768, 768, 768, 0);
  k_transpose_w<<<dim3(96, 24), tb, 0, stream>>>(w1, w1T, 768, 3072, 768, 0);
  k_transpose_w<<<dim3(24, 96), tb, 0, stream>>>(w2, w2T, 3072, 768, 3072, 0);
  k_pack_bias<<<9, 256, 0, stream>>>(bq, bk, bv, bqkv);

  // LN1 -> xn
  k_layernorm<<<2048, 256, 0, stream>>>(x, ln1_g, ln1_b, xn);
  // QKV projection (fused q|k|v; Q cols pre-scaled by log2e)
  k_gemm<0><<<dim3(18, 64), 256, 0, stream>>>(xn, wqkvT, bqkv, nullptr, qkvb, 8192, 2304, 768);
  // pack K (plain 16k frags) and V (kappa-permuted 32k frags)
  k_pack_ka<<<dim3(256, 2), 256, 0, stream>>>(qkvb, KA);
  k_pack_va<<<dim3(128, 2), 256, 0, stream>>>(qkvb, VA);
  // attention: 512 blocks x 16 waves, 133 KB LDS, slice pinned per XCD via bid&7
  k_attn<<<512, 1024, 0, stream>>>(qkvb, KA, VA, attn4);
  // sum 4 k-split slices
  k_reduce_attn<<<3072, 256, 0, stream>>>(attn4, attnr);
  // output projection + residual -> x1 (f32)
  k_gemm<1><<<dim3(6, 64), 256, 0, stream>>>(attnr, wpT, bp, x, x1, 8192, 768, 768);
  // LN2 -> xn2
  k_layernorm<<<2048, 256, 0, stream>>>(x1, ln2_g, ln2_b, xn2);
  // MLP1 + tanh-GELU -> hmid
  k_gemm<2><<<dim3(24, 64), 256, 0, stream>>>(xn2, w1T, b1, nullptr, hmid, 8192, 3072, 768);
  // MLP2 + residual -> out (f32)
  k_gemm<1><<<dim3(6, 64), 256, 0, stream>>>(hmid, w2T, b2, x1, (float*)d_out, 8192, 768, 3072);
}

// Round 10
// 469.949 us; speedup vs baseline: 1.1496x; 1.0584x over previous
//
#include <hip/hip_runtime.h>
#include <cstdint>
#include <cstddef>

#define AS1 __attribute__((address_space(1)))
#define AS3 __attribute__((address_space(3)))

typedef __attribute__((ext_vector_type(8))) __bf16 bf16x8;
typedef __attribute__((ext_vector_type(4))) float f32x4;

__device__ __forceinline__ void gload_lds16(const void* g, void* l) {
  __builtin_amdgcn_global_load_lds((AS1 void*)g, (AS3 void*)l, 16, 0, 0);
}

// ---------------- weight transpose f32 -> bf16 : dst[N][ldd] slice = src[K][N]^T ----------------
__global__ void k_transpose_w(const float* __restrict__ src, __bf16* __restrict__ dst,
                              int K, int N, int ldd, int koff) {
  __shared__ float tile[32][33];
  const int bx = blockIdx.x * 32;  // N dim
  const int by = blockIdx.y * 32;  // K dim
  const int tx = threadIdx.x, ty = threadIdx.y;
#pragma unroll
  for (int ii = 0; ii < 4; ++ii) {
    int i = ty + ii * 8;
    tile[i][tx] = src[(size_t)(by + i) * N + bx + tx];
  }
  __syncthreads();
#pragma unroll
  for (int ii = 0; ii < 4; ++ii) {
    int i = ty + ii * 8;
    dst[(size_t)(bx + i) * ldd + koff + by + tx] = (__bf16)tile[tx][i];
  }
}

// ---------------- pack qkv bias ----------------
__global__ void k_pack_bias(const float* __restrict__ bq, const float* __restrict__ bk,
                            const float* __restrict__ bv, float* __restrict__ dst) {
  int i = blockIdx.x * 256 + threadIdx.x;
  if (i < 768) dst[i] = bq[i];
  else if (i < 1536) dst[i] = bk[i - 768];
  else if (i < 2304) dst[i] = bv[i - 1536];
}

// ---------------- LayerNorm f32 -> bf16 (one wave per 768-row) ----------------
__global__ __launch_bounds__(256) void k_layernorm(const float* __restrict__ x,
                                                   const float* __restrict__ g,
                                                   const float* __restrict__ b,
                                                   __bf16* __restrict__ out) {
  const int row = blockIdx.x * 4 + (threadIdx.x >> 6);
  const int lane = threadIdx.x & 63;
  const float* xr = x + (size_t)row * 768;
  float4 v[3];
#pragma unroll
  for (int j = 0; j < 3; ++j) v[j] = *(const float4*)(xr + j * 256 + lane * 4);
  float s = 0.f, ss = 0.f;
#pragma unroll
  for (int j = 0; j < 3; ++j) {
    s += v[j].x + v[j].y + v[j].z + v[j].w;
    ss += v[j].x * v[j].x + v[j].y * v[j].y + v[j].z * v[j].z + v[j].w * v[j].w;
  }
#pragma unroll
  for (int off = 32; off > 0; off >>= 1) {
    s += __shfl_xor(s, off);
    ss += __shfl_xor(ss, off);
  }
  const float mu = s * (1.f / 768.f);
  const float rstd = rsqrtf(ss * (1.f / 768.f) - mu * mu + 1e-5f);
  __bf16* orow = out + (size_t)row * 768;
#pragma unroll
  for (int j = 0; j < 3; ++j) {
    float4 gg = *(const float4*)(g + j * 256 + lane * 4);
    float4 bb = *(const float4*)(b + j * 256 + lane * 4);
    const int base = j * 256 + lane * 4;
    orow[base + 0] = (__bf16)((v[j].x - mu) * rstd * gg.x + bb.x);
    orow[base + 1] = (__bf16)((v[j].y - mu) * rstd * gg.y + bb.y);
    orow[base + 2] = (__bf16)((v[j].z - mu) * rstd * gg.z + bb.z);
    orow[base + 3] = (__bf16)((v[j].w - mu) * rstd * gg.w + bb.w);
  }
}

// ---------------- GEMM: C[M][N] = A[M][K(lda)] * BT[N][K(ldb)]^T (+epilogue) ----------------
// 1-D grid with XCD-aware remap: xcd = bid&7 owns a contiguous band of M/128/8 row-groups
// over ALL column blocks -> A row-tiles become XCD-L2-resident (fetched ~once).
// MODE 0: +bias, store bf16; cols<768 (Q) pre-scaled by log2(e)
// MODE 1: +bias+resid, store f32
// MODE 2: +bias, tanh-GELU, store bf16
// MODE 3: split-K half (blockIdx.y = k-half); raw partial, store bf16 at half offset
template <int MODE>
__global__ __launch_bounds__(256) void k_gemm(const __bf16* __restrict__ A,
                                              const __bf16* __restrict__ BT,
                                              const float* __restrict__ bias,
                                              const float* __restrict__ resid,
                                              void* __restrict__ Cout,
                                              int M, int N, int K, int lda, int ldb) {
  __shared__ __bf16 As[128 * 32];
  __shared__ __bf16 Bs[128 * 32];
  const int nx = N >> 7;
  const int rpx = (M >> 7) >> 3;  // row-groups per XCD
  const int xcd = blockIdx.x & 7;
  const int ib = blockIdx.x >> 3;
  const int n0 = (ib % nx) << 7;
  const int m0 = (xcd * rpx + ib / nx) << 7;
  if constexpr (MODE == 3) {
    A += (size_t)blockIdx.y * K;   // k-half offset within lda-strided rows
    BT += (size_t)blockIdx.y * K;
  }
  const int tid = threadIdx.x;
  const int wid = tid >> 6, lane = tid & 63;
  const int wm = wid >> 1, wn = wid & 1;
  const int lr = lane & 15, lg = lane >> 4;

  f32x4 acc[4][4] = {};

  for (int k0 = 0; k0 < K; k0 += 32) {
#pragma unroll
    for (int it = 0; it < 2; ++it) {
      int t = tid + it * 256;
      int r = t >> 2, c = (t & 3) * 8;
      gload_lds16(A + (size_t)(m0 + r) * lda + k0 + c, As + t * 8);
      gload_lds16(BT + (size_t)(n0 + r) * ldb + k0 + c, Bs + t * 8);
    }
    __syncthreads();
    bf16x8 af[4], bf[4];
#pragma unroll
    for (int i = 0; i < 4; ++i) af[i] = *(const bf16x8*)(As + (wm * 64 + i * 16 + lr) * 32 + lg * 8);
#pragma unroll
    for (int j = 0; j < 4; ++j) bf[j] = *(const bf16x8*)(Bs + (wn * 64 + j * 16 + lr) * 32 + lg * 8);
#pragma unroll
    for (int i = 0; i < 4; ++i)
#pragma unroll
      for (int j = 0; j < 4; ++j)
        acc[i][j] = __builtin_amdgcn_mfma_f32_16x16x32_bf16(af[i], bf[j], acc[i][j], 0, 0, 0);
    __syncthreads();
  }

#pragma unroll
  for (int i = 0; i < 4; ++i)
#pragma unroll
    for (int j = 0; j < 4; ++j)
#pragma unroll
      for (int r = 0; r < 4; ++r) {
        int row = m0 + wm * 64 + i * 16 + lg * 4 + r;
        int col = n0 + wn * 64 + j * 16 + lr;
        float v = acc[i][j][r];
        if constexpr (MODE != 3) v += bias[col];
        size_t idx = (size_t)row * N + col;
        if constexpr (MODE == 0) {
          if (col < 768) v *= 1.44269504088896f;  // Q pre-scale: exp(x) = 2^(x*log2e)
          ((__bf16*)Cout)[idx] = (__bf16)v;
        } else if constexpr (MODE == 1) {
          ((float*)Cout)[idx] = v + resid[idx];
        } else if constexpr (MODE == 2) {
          float u = 0.7978845608f * (v + 0.044715f * v * v * v);
          float t = __builtin_amdgcn_exp2f(u * 2.88539008f);  // e^{2u}
          float th = 1.f - 2.f * __builtin_amdgcn_rcpf(t + 1.f);
          ((__bf16*)Cout)[idx] = (__bf16)(0.5f * v * (1.f + th));
        } else {
          ((__bf16*)Cout)[(size_t)blockIdx.y * M * N + idx] = (__bf16)v;
        }
      }
}

// ---------------- fuse MLP2 split-K partials: out = p0+p1+bias+resid (f32) ----------------
__global__ __launch_bounds__(256) void k_fuse_mlp2(const __bf16* __restrict__ p0,
                                                   const __bf16* __restrict__ p1,
                                                   const float* __restrict__ bias,
                                                   const float* __restrict__ resid,
                                                   float* __restrict__ out) {
  int g = blockIdx.x * 256 + threadIdx.x;  // 8 elems each; total 8192*768/8 = 786432
  int base = g * 8;
  int col = base % 768;
  bf16x8 a = *(const bf16x8*)(p0 + base);
  bf16x8 b = *(const bf16x8*)(p1 + base);
  float4 r0 = *(const float4*)(resid + base);
  float4 r1 = *(const float4*)(resid + base + 4);
  float4 b0 = *(const float4*)(bias + col);
  float4 b1 = *(const float4*)(bias + col + 4);
  float4 o0, o1;
  o0.x = r0.x + b0.x + (float)a[0] + (float)b[0];
  o0.y = r0.y + b0.y + (float)a[1] + (float)b[1];
  o0.z = r0.z + b0.z + (float)a[2] + (float)b[2];
  o0.w = r0.w + b0.w + (float)a[3] + (float)b[3];
  o1.x = r1.x + b1.x + (float)a[4] + (float)b[4];
  o1.y = r1.y + b1.y + (float)a[5] + (float)b[5];
  o1.z = r1.z + b1.z + (float)a[6] + (float)b[6];
  o1.w = r1.w + b1.w + (float)a[7] + (float)b[7];
  *(float4*)(out + base) = o0;
  *(float4*)(out + base + 4) = o1;
}

// ---------------- pack K into fragment-major KA16 (plain rows, 16-k granules) ----------------
// KA16[b][kb16][hp][hh][dc][lane][8] = K[b][kb*16 + (lane&15)][hp*192+hh*96+dc*32+(lane>>4)*8 + e]
__global__ __launch_bounds__(256) void k_pack_ka(const __bf16* __restrict__ qkv,
                                                 __bf16* __restrict__ KA) {
  const int kb = blockIdx.x, b = blockIdx.y;  // kb in [0,256)
  const int t = threadIdx.x;
#pragma unroll
  for (int i = 0; i < 6; ++i) {
    int c = t + i * 256;  // [0,1536)
    int lane = c & 63, f = c >> 6;  // f in [0,24)
    int dc = f % 3, hh = (f / 3) & 1, hp = f / 6;
    int row = kb * 16 + (lane & 15);
    int col = 768 + hp * 192 + hh * 96 + dc * 32 + (lane >> 4) * 8;
    bf16x8 v = *(const bf16x8*)(qkv + (size_t)(b * 4096 + row) * 2304 + col);
    *(bf16x8*)(KA + ((size_t)(b * 256 + kb) * 1536 + c) * 8) = v;
  }
}

// ---------------- pack V, kappa-permuted, fragment-major VA32 (32-k granules) ----------------
// VA32[b][g][hp][hh][db][lane][e] = V[b][g*32 + kappa][hp*192+hh*96+db*16+(lane&15)]
// kappa(lg,e) = (e>>2)*16 + lg*4 + (e&3)  -- matches P-register slot order of two 16-k QK tiles.
__global__ __launch_bounds__(256) void k_pack_va(const __bf16* __restrict__ qkv,
                                                 __bf16* __restrict__ VA) {
  __shared__ __bf16 vtile[32][772];
  const int g = blockIdx.x, b = blockIdx.y;  // g in [0,128)
  const int t = threadIdx.x;
#pragma unroll
  for (int i = 0; i < 12; ++i) {
    int c = t + i * 256;
    int row = c / 96, c8 = c % 96;
    *(bf16x8*)(&vtile[row][c8 * 8]) =
        *(const bf16x8*)(qkv + (size_t)(b * 4096 + g * 32 + row) * 2304 + 1536 + c8 * 8);
  }
  __syncthreads();
#pragma unroll
  for (int i = 0; i < 12; ++i) {
    int c = t + i * 256;  // [0,3072)
    int lane = c & 63, f = c >> 6;  // f in [0,48)
    int db = f % 6, hh = (f / 6) & 1, hp = f / 12;
    int d = hp * 192 + hh * 96 + db * 16 + (lane & 15);
    int lg_ = lane >> 4;
    bf16x8 v;
#pragma unroll
    for (int e = 0; e < 8; ++e) {
      int krow = (e >> 2) * 16 + lg_ * 4 + (e & 3);
      v[e] = vtile[krow][d];
    }
    *(bf16x8*)(VA + ((size_t)(b * 128 + g) * 3072 + c) * 8) = v;
  }
}

// ---------------- fused attention v9: LDS-shared K/V + counted vmcnt + raw v_exp_f32 -------
__global__ __launch_bounds__(1024, 4) void k_attn(const __bf16* __restrict__ qkv,
                                                  const __bf16* __restrict__ KA,
                                                  const __bf16* __restrict__ VA,
                                                  __bf16* __restrict__ attn4) {
  __shared__ __bf16 Kb_s[2][12288];   // 2 x 24.6 KB (16k x 4hp)
  __shared__ __bf16 Vb_s[24576];      // 49.2 KB (32k x 4hp)
  __shared__ float ps_s[2][4352];     // 2 x [4qs][16kslot][4hp][17]
  const int bid = blockIdx.x;
  const int slice = bid & 7;
  const int b = slice >> 2, ks = slice & 3;
  const int qb = bid >> 3;
  const int wid = threadIdx.x >> 6;
  const int qs = wid & 3, hp = wid >> 2;
  const int q0 = qb * 64 + qs * 16;
  const int lane = threadIdx.x & 63;
  const int lr = lane & 15, lg = lane >> 4;

  // Q fragments (one-time 16-row gather, reused 64 rounds)
  const __bf16* Qb = qkv + (size_t)(b * 4096 + q0) * 2304;
  bf16x8 qf[2][3];
#pragma unroll
  for (int hh = 0; hh < 2; ++hh)
#pragma unroll
    for (int dc = 0; dc < 3; ++dc)
      qf[hh][dc] = *(const bf16x8*)(Qb + (size_t)lr * 2304 + (hp * 2 + hh) * 96 + dc * 32 + lg * 8);

  // staging work split: K = 24 x 1KB loads (waves 0..7 take 2, 8..15 take 1); V = 48, 3 per wave
  const int L1 = wid, hpK1 = L1 / 6, jK1 = L1 - hpK1 * 6;
  const int L2 = wid + 16, hpK2 = L2 / 6, jK2 = L2 - hpK2 * 6;

  int kb = ks * 64;
  // prologue: stage K(kb0) into buffer 0
  {
    const __bf16* srcK = KA + (size_t)(b * 256 + kb) * 12288;
    gload_lds16(srcK + hpK1 * 3072 + jK1 * 512 + lane * 8,
                &Kb_s[0][hpK1 * 3072 + jK1 * 512 + lane * 8]);
    if (wid < 8)
      gload_lds16(srcK + hpK2 * 3072 + jK2 * 512 + lane * 8,
                  &Kb_s[0][hpK2 * 3072 + jK2 * 512 + lane * 8]);
  }
  asm volatile("s_waitcnt vmcnt(0)" ::: "memory");
  __builtin_amdgcn_s_barrier();
  asm volatile("" ::: "memory");

  f32x4 o[2][6] = {};
  f32x4 eA[2], eB[2];  // [hh] energy tiles for the two 16-k halves of a 32-k group

#define HALF(ET, PAR, DO_V, DO_PV) do {                                               \
    { /* stage K(kb+1) FIRST (drained at this round's barrier) */                     \
      size_t kidx = (size_t)(b * 256 + kb + 1);                                       \
      if (kidx > 511) kidx = 511;                                                     \
      const __bf16* srcK = KA + kidx * 12288;                                         \
      gload_lds16(srcK + hpK1 * 3072 + jK1 * 512 + lane * 8,                          \
                  &Kb_s[PAR ^ 1][hpK1 * 3072 + jK1 * 512 + lane * 8]);                \
      if (wid < 8)                                                                    \
        gload_lds16(srcK + hpK2 * 3072 + jK2 * 512 + lane * 8,                        \
                    &Kb_s[PAR ^ 1][hpK2 * 3072 + jK2 * 512 + lane * 8]);              \
    }                                                                                 \
    if (DO_V) { /* stage V second: stays in flight until the NEXT (odd) barrier */    \
      const __bf16* srcV = VA + (size_t)(b * 128 + (kb >> 1)) * 24576;                \
      _Pragma("unroll")                                                               \
      for (int tt = 0; tt < 3; ++tt) {                                                \
        int L = wid * 3 + tt;                                                         \
        int hpV = L / 12, jV = L - hpV * 12;                                          \
        gload_lds16(srcV + hpV * 6144 + jV * 512 + lane * 8,                          \
                    &Vb_s[hpV * 6144 + jV * 512 + lane * 8]);                         \
      }                                                                               \
    }                                                                                 \
    /* QK^T from LDS */                                                               \
    ET[0] = (f32x4){0.f, 0.f, 0.f, 0.f};                                              \
    ET[1] = (f32x4){0.f, 0.f, 0.f, 0.f};                                              \
    {                                                                                 \
      const __bf16* kbase = &Kb_s[PAR][hp * 3072 + lane * 8];                         \
      __builtin_amdgcn_s_setprio(1);                                                  \
      _Pragma("unroll")                                                               \
      for (int hh = 0; hh < 2; ++hh)                                                  \
        _Pragma("unroll")                                                             \
        for (int dc = 0; dc < 3; ++dc) {                                              \
          bf16x8 kf = *(const bf16x8*)(kbase + (hh * 3 + dc) * 512);                  \
          ET[hh] = __builtin_amdgcn_mfma_f32_16x16x32_bf16(kf, qf[hh][dc], ET[hh],    \
                                                           0, 0, 0);                  \
        }                                                                             \
      __builtin_amdgcn_s_setprio(0);                                                  \
    }                                                                                 \
    /* raw 2^x (Q pre-scaled by log2e) + 2-head partial sums -> psum[PAR] */          \
    _Pragma("unroll")                                                                 \
    for (int rr = 0; rr < 4; ++rr) {                                                  \
      float e0 = __builtin_amdgcn_exp2f(ET[0][rr]);                                   \
      float e1 = __builtin_amdgcn_exp2f(ET[1][rr]);                                   \
      ET[0][rr] = e0;                                                                 \
      ET[1][rr] = e1;                                                                 \
      ps_s[PAR][qs * 1088 + (lg * 4 + rr) * 68 + hp * 17 + lr] = e0 + e1;             \
    }                                                                                 \
    if (DO_V) {                                                                       \
      asm volatile("s_waitcnt vmcnt(3) lgkmcnt(0)" ::: "memory");                     \
    } else {                                                                          \
      asm volatile("s_waitcnt vmcnt(0) lgkmcnt(0)" ::: "memory");                     \
    }                                                                                 \
    __builtin_amdgcn_s_barrier();                                                     \
    asm volatile("" ::: "memory");                                                    \
    /* denominator exchange + normalize in-register */                                \
    {                                                                                 \
      float inv_[4];                                                                  \
      _Pragma("unroll")                                                               \
      for (int rr = 0; rr < 4; ++rr) {                                                \
        const int base = qs * 1088 + (lg * 4 + rr) * 68 + lr;                         \
        float tot = (ps_s[PAR][base] + ps_s[PAR][base + 17]) +                        \
                    (ps_s[PAR][base + 34] + ps_s[PAR][base + 51]);                    \
        inv_[rr] = 0.03608439182435161f * __builtin_amdgcn_rcpf(tot);                 \
      }                                                                               \
      _Pragma("unroll")                                                               \
      for (int rr = 0; rr < 4; ++rr) {                                                \
        ET[0][rr] *= inv_[rr];                                                        \
        ET[1][rr] *= inv_[rr];                                                        \
      }                                                                               \
    }                                                                                 \
    if (DO_PV) { /* PV over the 32-k group from eA,eB (kappa-matched VA) */           \
      bf16x8 pf0, pf1;                                                                \
      _Pragma("unroll")                                                               \
      for (int e2 = 0; e2 < 8; ++e2) {                                                \
        int rr = e2 & 3;                                                              \
        if (e2 < 4) { pf0[e2] = (__bf16)eA[0][rr]; pf1[e2] = (__bf16)eA[1][rr]; }     \
        else        { pf0[e2] = (__bf16)eB[0][rr]; pf1[e2] = (__bf16)eB[1][rr]; }     \
      }                                                                               \
      const __bf16* vbase = &Vb_s[hp * 6144 + lane * 8];                              \
      __builtin_amdgcn_s_setprio(1);                                                  \
      _Pragma("unroll")                                                               \
      for (int db = 0; db < 6; ++db) {                                                \
        bf16x8 vf0 = *(const bf16x8*)(vbase + db * 512);                              \
        bf16x8 vf1 = *(const bf16x8*)(vbase + (6 + db) * 512);                        \
        o[0][db] = __builtin_amdgcn_mfma_f32_16x16x32_bf16(pf0, vf0, o[0][db], 0, 0, 0); \
        o[1][db] = __builtin_amdgcn_mfma_f32_16x16x32_bf16(pf1, vf1, o[1][db], 0, 0, 0); \
      }                                                                               \
      __builtin_amdgcn_s_setprio(0);                                                  \
    }                                                                                 \
    ++kb;                                                                             \
  } while (0)

  for (int rp = 0; rp < 64; rp += 2) {
    HALF(eA, 0, 1, 0);  // even 16-k half: stages V(group), no PV
    HALF(eB, 1, 0, 1);  // odd half: PV over the full 32-k group
  }
#undef HALF

#pragma unroll
  for (int hh = 0; hh < 2; ++hh)
#pragma unroll
    for (int db = 0; db < 6; ++db)
#pragma unroll
      for (int rr = 0; rr < 4; ++rr)
        attn4[(size_t)(b * 4096 + q0 + lg * 4 + rr) * 3072 + ks * 768 +
              (hp * 2 + hh) * 96 + db * 16 + lr] = (__bf16)o[hh][db][rr];
}

// ---------------- reduce 4 k-split slices -> bf16 ----------------
__global__ __launch_bounds__(256) void k_reduce_attn(const __bf16* __restrict__ attn4,
                                                     __bf16* __restrict__ out) {
  int g = blockIdx.x * 256 + threadIdx.x;  // chunk of 8, total 8192*96
  int row = g / 96, c8 = g % 96;
  const __bf16* p = attn4 + (size_t)row * 3072 + c8 * 8;
  float acc[8] = {};
#pragma unroll
  for (int s = 0; s < 4; ++s) {
    bf16x8 v = *(const bf16x8*)(p + s * 768);
#pragma unroll
    for (int e = 0; e < 8; ++e) acc[e] += (float)v[e];
  }
  bf16x8 r;
#pragma unroll
  for (int e = 0; e < 8; ++e) r[e] = (__bf16)acc[e];
  *(bf16x8*)(out + (size_t)row * 768 + c8 * 8) = r;
}

// ---------------- launcher ----------------
extern "C" void kernel_launch(void* const* d_in, const int* in_sizes, int n_in,
                              void* d_out, int out_size, void* d_ws, size_t ws_size,
                              hipStream_t stream) {
  (void)in_sizes; (void)n_in; (void)out_size; (void)ws_size;
  const float* x     = (const float*)d_in[0];
  const float* ln1_g = (const float*)d_in[1];
  const float* ln1_b = (const float*)d_in[2];
  const float* wq    = (const float*)d_in[3];
  const float* bq    = (const float*)d_in[4];
  const float* wk    = (const float*)d_in[5];
  const float* bk    = (const float*)d_in[6];
  const float* wv    = (const float*)d_in[7];
  const float* bv    = (const float*)d_in[8];
  const float* wp    = (const float*)d_in[9];
  const float* bp    = (const float*)d_in[10];
  const float* ln2_g = (const float*)d_in[11];
  const float* ln2_b = (const float*)d_in[12];
  const float* w1    = (const float*)d_in[13];
  const float* b1    = (const float*)d_in[14];
  const float* w2    = (const float*)d_in[15];
  const float* b2    = (const float*)d_in[16];

  char* ws = (char*)d_ws;
  const size_t o_wqkvT = 0;                                   // [2304][768] bf16
  const size_t o_wpT   = o_wqkvT + (size_t)2304 * 768 * 2;    // [768][768] bf16
  const size_t o_w1T   = o_wpT   + (size_t)768 * 768 * 2;     // [3072][768] bf16
  const size_t o_w2T   = o_w1T   + (size_t)768 * 3072 * 2;    // [768][3072] bf16
  const size_t o_bqkv  = o_w2T   + (size_t)3072 * 768 * 2;    // [2304] f32
  const size_t o_xn    = o_bqkv  + (size_t)2304 * 4;          // [8192][768] bf16
  const size_t o_qkv   = o_xn    + (size_t)8192 * 768 * 2;    // [8192][2304] bf16
  const size_t o_KA    = o_qkv   + (size_t)8192 * 2304 * 2;   // [2][256][1536][8] bf16
  const size_t o_VA    = o_KA    + (size_t)2 * 256 * 1536 * 8 * 2;
  const size_t o_attn4 = o_VA    + (size_t)2 * 128 * 3072 * 8 * 2;  // [8192][3072] bf16
  // aliases (lifetime-disjoint):
  const size_t o_x1      = o_attn4;                               // [8192][768] f32
  const size_t o_part    = o_attn4 + (size_t)8192 * 768 * 4;      // [2][8192][768] bf16
  const size_t o_attnred = o_KA;     // [8192][768] bf16 (KA dead after attention)
  const size_t o_xn2     = o_VA;     // [8192][768] bf16 (VA dead after attention)
  const size_t o_hmid    = o_xn;     // [8192][3072] bf16 (spans xn+qkv, both dead)

  __bf16* wqkvT = (__bf16*)(ws + o_wqkvT);
  __bf16* wpT   = (__bf16*)(ws + o_wpT);
  __bf16* w1T   = (__bf16*)(ws + o_w1T);
  __bf16* w2T   = (__bf16*)(ws + o_w2T);
  float*  bqkv  = (float*)(ws + o_bqkv);
  __bf16* xn    = (__bf16*)(ws + o_xn);
  __bf16* qkvb  = (__bf16*)(ws + o_qkv);
  __bf16* KA    = (__bf16*)(ws + o_KA);
  __bf16* VA    = (__bf16*)(ws + o_VA);
  __bf16* attn4 = (__bf16*)(ws + o_attn4);
  float*  x1    = (float*)(ws + o_x1);
  __bf16* part  = (__bf16*)(ws + o_part);
  __bf16* attnr = (__bf16*)(ws + o_attnred);
  __bf16* xn2   = (__bf16*)(ws + o_xn2);
  __bf16* hmid  = (__bf16*)(ws + o_hmid);

  dim3 tb(32, 8);
  k_transpose_w<<<dim3(24, 24), tb, 0, stream>>>(wq, wqkvT, 768, 768, 768, 0);
  k_transpose_w<<<dim3(24, 24), tb, 0, stream>>>(wk, wqkvT + (size_t)768 * 768, 768, 768, 768, 0);
  k_transpose_w<<<dim3(24, 24), tb, 0, stream>>>(wv, wqkvT + (size_t)2 * 768 * 768, 768, 768, 768, 0);
  k_transpose_w<<<dim3(24, 24), tb, 0, stream>>>(wp, wpT, 768, 768, 768, 0);
  k_transpose_w<<<dim3(96, 24), tb, 0, stream>>>(w1, w1T, 768, 3072, 768, 0);
  k_transpose_w<<<dim3(24, 96), tb, 0, stream>>>(w2, w2T, 3072, 768, 3072, 0);
  k_pack_bias<<<9, 256, 0, stream>>>(bq, bk, bv, bqkv);

  // LN1 -> xn
  k_layernorm<<<2048, 256, 0, stream>>>(x, ln1_g, ln1_b, xn);
  // QKV projection (fused q|k|v; Q cols pre-scaled by log2e)
  k_gemm<0><<<1152, 256, 0, stream>>>(xn, wqkvT, bqkv, nullptr, qkvb, 8192, 2304, 768, 768, 768);
  // pack K (plain 16k frags) and V (kappa-permuted 32k frags)
  k_pack_ka<<<dim3(256, 2), 256, 0, stream>>>(qkvb, KA);
  k_pack_va<<<dim3(128, 2), 256, 0, stream>>>(qkvb, VA);
  // attention: 512 blocks x 16 waves, 133 KB LDS, slice pinned per XCD via bid&7
  k_attn<<<512, 1024, 0, stream>>>(qkvb, KA, VA, attn4);
  // sum 4 k-split slices
  k_reduce_attn<<<3072, 256, 0, stream>>>(attn4, attnr);
  // output projection + residual -> x1 (f32)
  k_gemm<1><<<384, 256, 0, stream>>>(attnr, wpT, bp, x, x1, 8192, 768, 768, 768, 768);
  // LN2 -> xn2
  k_layernorm<<<2048, 256, 0, stream>>>(x1, ln2_g, ln2_b, xn2);
  // MLP1 + tanh-GELU -> hmid
  k_gemm<2><<<1536, 256, 0, stream>>>(xn2, w1T, b1, nullptr, hmid, 8192, 3072, 768, 768, 768);
  // MLP2 split-K=2 (concurrent halves -> bf16 partials), then fuse
  k_gemm<3><<<dim3(384, 2), 256, 0, stream>>>(hmid, w2T, nullptr, nullptr, part,
                                              8192, 768, 1536, 3072, 3072);
  k_fuse_mlp2<<<3072, 256, 0, stream>>>(part, part + (size_t)8192 * 768, b2, x1,
                                        (float*)d_out);
}

// Round 11
// 445.919 us; speedup vs baseline: 1.2115x; 1.0539x over previous
//
#include <hip/hip_runtime.h>
#include <cstdint>
#include <cstddef>

#define AS1 __attribute__((address_space(1)))
#define AS3 __attribute__((address_space(3)))

typedef __attribute__((ext_vector_type(8))) __bf16 bf16x8;
typedef __attribute__((ext_vector_type(4))) float f32x4;

__device__ __forceinline__ void gload_lds16(const void* g, void* l) {
  __builtin_amdgcn_global_load_lds((AS1 void*)g, (AS3 void*)l, 16, 0, 0);
}

// ---------------- weight transpose f32 -> bf16 : dst[N][ldd] = src[K][N]^T ----------------
__global__ void k_transpose_w(const float* __restrict__ src, __bf16* __restrict__ dst,
                              int K, int N, int ldd, int koff) {
  __shared__ float tile[32][33];
  const int bx = blockIdx.x * 32;  // N dim
  const int by = blockIdx.y * 32;  // K dim
  const int tx = threadIdx.x, ty = threadIdx.y;
#pragma unroll
  for (int ii = 0; ii < 4; ++ii) {
    int i = ty + ii * 8;
    tile[i][tx] = src[(size_t)(by + i) * N + bx + tx];
  }
  __syncthreads();
#pragma unroll
  for (int ii = 0; ii < 4; ++ii) {
    int i = ty + ii * 8;
    dst[(size_t)(bx + i) * ldd + koff + by + tx] = (__bf16)tile[tx][i];
  }
}

// ---------------- 4x 768x768 weight transposes in one launch (z picks matrix) ----------------
__global__ void k_transpose_w4(const float* __restrict__ s0, const float* __restrict__ s1,
                               const float* __restrict__ s2, const float* __restrict__ s3,
                               __bf16* __restrict__ d0, __bf16* __restrict__ d1,
                               __bf16* __restrict__ d2, __bf16* __restrict__ d3) {
  __shared__ float tile[32][33];
  const float* src;
  __bf16* dst;
  switch (blockIdx.z) {
    case 0: src = s0; dst = d0; break;
    case 1: src = s1; dst = d1; break;
    case 2: src = s2; dst = d2; break;
    default: src = s3; dst = d3; break;
  }
  const int bx = blockIdx.x * 32, by = blockIdx.y * 32;
  const int tx = threadIdx.x, ty = threadIdx.y;
#pragma unroll
  for (int ii = 0; ii < 4; ++ii) {
    int i = ty + ii * 8;
    tile[i][tx] = src[(size_t)(by + i) * 768 + bx + tx];
  }
  __syncthreads();
#pragma unroll
  for (int ii = 0; ii < 4; ++ii) {
    int i = ty + ii * 8;
    dst[(size_t)(bx + i) * 768 + by + tx] = (__bf16)tile[tx][i];
  }
}

// ---------------- pack qkv bias ----------------
__global__ void k_pack_bias(const float* __restrict__ bq, const float* __restrict__ bk,
                            const float* __restrict__ bv, float* __restrict__ dst) {
  int i = blockIdx.x * 256 + threadIdx.x;
  if (i < 768) dst[i] = bq[i];
  else if (i < 1536) dst[i] = bk[i - 768];
  else if (i < 2304) dst[i] = bv[i - 1536];
}

// ---------------- LayerNorm f32 -> bf16 (one wave per 768-row) ----------------
__global__ __launch_bounds__(256) void k_layernorm(const float* __restrict__ x,
                                                   const float* __restrict__ g,
                                                   const float* __restrict__ b,
                                                   __bf16* __restrict__ out) {
  const int row = blockIdx.x * 4 + (threadIdx.x >> 6);
  const int lane = threadIdx.x & 63;
  const float* xr = x + (size_t)row * 768;
  float4 v[3];
#pragma unroll
  for (int j = 0; j < 3; ++j) v[j] = *(const float4*)(xr + j * 256 + lane * 4);
  float s = 0.f, ss = 0.f;
#pragma unroll
  for (int j = 0; j < 3; ++j) {
    s += v[j].x + v[j].y + v[j].z + v[j].w;
    ss += v[j].x * v[j].x + v[j].y * v[j].y + v[j].z * v[j].z + v[j].w * v[j].w;
  }
#pragma unroll
  for (int off = 32; off > 0; off >>= 1) {
    s += __shfl_xor(s, off);
    ss += __shfl_xor(ss, off);
  }
  const float mu = s * (1.f / 768.f);
  const float rstd = rsqrtf(ss * (1.f / 768.f) - mu * mu + 1e-5f);
  __bf16* orow = out + (size_t)row * 768;
#pragma unroll
  for (int j = 0; j < 3; ++j) {
    float4 gg = *(const float4*)(g + j * 256 + lane * 4);
    float4 bb = *(const float4*)(b + j * 256 + lane * 4);
    const int base = j * 256 + lane * 4;
    orow[base + 0] = (__bf16)((v[j].x - mu) * rstd * gg.x + bb.x);
    orow[base + 1] = (__bf16)((v[j].y - mu) * rstd * gg.y + bb.y);
    orow[base + 2] = (__bf16)((v[j].z - mu) * rstd * gg.z + bb.z);
    orow[base + 3] = (__bf16)((v[j].w - mu) * rstd * gg.w + bb.w);
  }
}

// ---------------- GEMM: C[M][N] = A[M][K(lda)] * BT[N][K(ldb)]^T (+epilogue) ----------------
// 1-D grid, XCD-aware remap: xcd = bid&7 owns a contiguous band of row-groups.
// MODE 0: +bias, store bf16; cols<768 (Q) pre-scaled by log2(e)
// MODE 1: +bias+resid, store f32
// MODE 2: +bias, tanh-GELU, store bf16
// MODE 3: split-K half (blockIdx.y = k-half); raw partial, store bf16 at half offset
template <int MODE>
__global__ __launch_bounds__(256) void k_gemm(const __bf16* __restrict__ A,
                                              const __bf16* __restrict__ BT,
                                              const float* __restrict__ bias,
                                              const float* __restrict__ resid,
                                              void* __restrict__ Cout,
                                              int M, int N, int K, int lda, int ldb) {
  __shared__ __bf16 As[128 * 32];
  __shared__ __bf16 Bs[128 * 32];
  const int nx = N >> 7;
  const int rpx = (M >> 7) >> 3;  // row-groups per XCD
  const int xcd = blockIdx.x & 7;
  const int ib = blockIdx.x >> 3;
  const int n0 = (ib % nx) << 7;
  const int m0 = (xcd * rpx + ib / nx) << 7;
  if constexpr (MODE == 3) {
    A += (size_t)blockIdx.y * K;
    BT += (size_t)blockIdx.y * K;
  }
  const int tid = threadIdx.x;
  const int wid = tid >> 6, lane = tid & 63;
  const int wm = wid >> 1, wn = wid & 1;
  const int lr = lane & 15, lg = lane >> 4;

  f32x4 acc[4][4] = {};

  for (int k0 = 0; k0 < K; k0 += 32) {
#pragma unroll
    for (int it = 0; it < 2; ++it) {
      int t = tid + it * 256;
      int r = t >> 2, c = (t & 3) * 8;
      gload_lds16(A + (size_t)(m0 + r) * lda + k0 + c, As + t * 8);
      gload_lds16(BT + (size_t)(n0 + r) * ldb + k0 + c, Bs + t * 8);
    }
    __syncthreads();
    bf16x8 af[4], bf[4];
#pragma unroll
    for (int i = 0; i < 4; ++i) af[i] = *(const bf16x8*)(As + (wm * 64 + i * 16 + lr) * 32 + lg * 8);
#pragma unroll
    for (int j = 0; j < 4; ++j) bf[j] = *(const bf16x8*)(Bs + (wn * 64 + j * 16 + lr) * 32 + lg * 8);
#pragma unroll
    for (int i = 0; i < 4; ++i)
#pragma unroll
      for (int j = 0; j < 4; ++j)
        acc[i][j] = __builtin_amdgcn_mfma_f32_16x16x32_bf16(af[i], bf[j], acc[i][j], 0, 0, 0);
    __syncthreads();
  }

#pragma unroll
  for (int i = 0; i < 4; ++i)
#pragma unroll
    for (int j = 0; j < 4; ++j)
#pragma unroll
      for (int r = 0; r < 4; ++r) {
        int row = m0 + wm * 64 + i * 16 + lg * 4 + r;
        int col = n0 + wn * 64 + j * 16 + lr;
        float v = acc[i][j][r];
        if constexpr (MODE != 3) v += bias[col];
        size_t idx = (size_t)row * N + col;
        if constexpr (MODE == 0) {
          if (col < 768) v *= 1.44269504088896f;  // Q pre-scale: exp(x) = 2^(x*log2e)
          ((__bf16*)Cout)[idx] = (__bf16)v;
        } else if constexpr (MODE == 1) {
          ((float*)Cout)[idx] = v + resid[idx];
        } else if constexpr (MODE == 2) {
          float u = 0.7978845608f * (v + 0.044715f * v * v * v);
          float t = __builtin_amdgcn_exp2f(u * 2.88539008f);  // e^{2u}
          float th = 1.f - 2.f * __builtin_amdgcn_rcpf(t + 1.f);
          ((__bf16*)Cout)[idx] = (__bf16)(0.5f * v * (1.f + th));
        } else {
          ((__bf16*)Cout)[(size_t)blockIdx.y * M * N + idx] = (__bf16)v;
        }
      }
}

// ---------------- fuse MLP2 split-K partials: out = p0+p1+bias+resid (f32) ----------------
__global__ __launch_bounds__(256) void k_fuse_mlp2(const __bf16* __restrict__ p0,
                                                   const __bf16* __restrict__ p1,
                                                   const float* __restrict__ bias,
                                                   const float* __restrict__ resid,
                                                   float* __restrict__ out) {
  int g = blockIdx.x * 256 + threadIdx.x;
  int base = g * 8;
  int col = base % 768;
  bf16x8 a = *(const bf16x8*)(p0 + base);
  bf16x8 b = *(const bf16x8*)(p1 + base);
  float4 r0 = *(const float4*)(resid + base);
  float4 r1 = *(const float4*)(resid + base + 4);
  float4 b0 = *(const float4*)(bias + col);
  float4 b1 = *(const float4*)(bias + col + 4);
  float4 o0, o1;
  o0.x = r0.x + b0.x + (float)a[0] + (float)b[0];
  o0.y = r0.y + b0.y + (float)a[1] + (float)b[1];
  o0.z = r0.z + b0.z + (float)a[2] + (float)b[2];
  o0.w = r0.w + b0.w + (float)a[3] + (float)b[3];
  o1.x = r1.x + b1.x + (float)a[4] + (float)b[4];
  o1.y = r1.y + b1.y + (float)a[5] + (float)b[5];
  o1.z = r1.z + b1.z + (float)a[6] + (float)b[6];
  o1.w = r1.w + b1.w + (float)a[7] + (float)b[7];
  *(float4*)(out + base) = o0;
  *(float4*)(out + base + 4) = o1;
}

// ---------------- merged K/V pack (per 32-row group g): KA granules 2g,2g+1 + VA group g ----
// KA16[b][kb16][hp][hh][dc][lane][8] = K[b][kb*16 + (lane&15)][hp*192+hh*96+dc*32+(lane>>4)*8+e]
// VA32[b][g][hp][hh][db][lane][e]   = V[b][g*32 + kappa(lane>>4,e)][hp*192+hh*96+db*16+(lane&15)]
// kappa(lg,e) = (e>>2)*16 + lg*4 + (e&3)
__global__ __launch_bounds__(256) void k_pack_kv(const __bf16* __restrict__ qkv,
                                                 __bf16* __restrict__ KA,
                                                 __bf16* __restrict__ VA) {
  __shared__ __bf16 vtile[32][772];
  const int g = blockIdx.x, b = blockIdx.y;  // g in [0,128)
  const int t = threadIdx.x;
  // KA: two 16-row granules
#pragma unroll
  for (int half = 0; half < 2; ++half) {
    int kb = g * 2 + half;
#pragma unroll
    for (int i = 0; i < 6; ++i) {
      int c = t + i * 256;  // [0,1536)
      int lane = c & 63, f = c >> 6;
      int dc = f % 3, hh = (f / 3) & 1, hp = f / 6;
      int row = kb * 16 + (lane & 15);
      int col = 768 + hp * 192 + hh * 96 + dc * 32 + (lane >> 4) * 8;
      bf16x8 v = *(const bf16x8*)(qkv + (size_t)(b * 4096 + row) * 2304 + col);
      *(bf16x8*)(KA + ((size_t)(b * 256 + kb) * 1536 + c) * 8) = v;
    }
  }
  // VA: kappa-permuted via LDS tile
#pragma unroll
  for (int i = 0; i < 12; ++i) {
    int c = t + i * 256;
    int row = c / 96, c8 = c % 96;
    *(bf16x8*)(&vtile[row][c8 * 8]) =
        *(const bf16x8*)(qkv + (size_t)(b * 4096 + g * 32 + row) * 2304 + 1536 + c8 * 8);
  }
  __syncthreads();
#pragma unroll
  for (int i = 0; i < 12; ++i) {
    int c = t + i * 256;  // [0,3072)
    int lane = c & 63, f = c >> 6;
    int db = f % 6, hh = (f / 6) & 1, hp = f / 12;
    int d = hp * 192 + hh * 96 + db * 16 + (lane & 15);
    int lg_ = lane >> 4;
    bf16x8 v;
#pragma unroll
    for (int e = 0; e < 8; ++e) {
      int krow = (e >> 2) * 16 + lg_ * 4 + (e & 3);
      v[e] = vtile[krow][d];
    }
    *(bf16x8*)(VA + ((size_t)(b * 128 + g) * 3072 + c) * 8) = v;
  }
}

// ---------------- fused attention v10: ks=2, 256 blocks (1/CU), LDS-shared K/V ----------------
// slice = bid&3 -> (b = slice>>1, ks = slice&1); qb = bid>>2 (64 q-rows each).
// 16 waves = (qs 0..3) x (hp 0..3). 128 rounds of 16 k; K dbuf, V single 32k buffer.
// Counted vmcnt at even barriers (V loads span to the odd barrier). Output [8192][2*768].
__global__ __launch_bounds__(1024, 4) void k_attn(const __bf16* __restrict__ qkv,
                                                  const __bf16* __restrict__ KA,
                                                  const __bf16* __restrict__ VA,
                                                  __bf16* __restrict__ attn2) {
  __shared__ __bf16 Kb_s[2][12288];
  __shared__ __bf16 Vb_s[24576];
  __shared__ float ps_s[2][4352];
  const int bid = blockIdx.x;
  const int slice = bid & 3;
  const int b = slice >> 1, ks = slice & 1;
  const int qb = bid >> 2;
  const int wid = threadIdx.x >> 6;
  const int qs = wid & 3, hp = wid >> 2;
  const int q0 = qb * 64 + qs * 16;
  const int lane = threadIdx.x & 63;
  const int lr = lane & 15, lg = lane >> 4;

  const __bf16* Qb = qkv + (size_t)(b * 4096 + q0) * 2304;
  bf16x8 qf[2][3];
#pragma unroll
  for (int hh = 0; hh < 2; ++hh)
#pragma unroll
    for (int dc = 0; dc < 3; ++dc)
      qf[hh][dc] = *(const bf16x8*)(Qb + (size_t)lr * 2304 + (hp * 2 + hh) * 96 + dc * 32 + lg * 8);

  const int L1 = wid, hpK1 = L1 / 6, jK1 = L1 - hpK1 * 6;
  const int L2 = wid + 16, hpK2 = L2 / 6, jK2 = L2 - hpK2 * 6;

  int kb = ks * 128;
  {
    const __bf16* srcK = KA + (size_t)(b * 256 + kb) * 12288;
    gload_lds16(srcK + hpK1 * 3072 + jK1 * 512 + lane * 8,
                &Kb_s[0][hpK1 * 3072 + jK1 * 512 + lane * 8]);
    if (wid < 8)
      gload_lds16(srcK + hpK2 * 3072 + jK2 * 512 + lane * 8,
                  &Kb_s[0][hpK2 * 3072 + jK2 * 512 + lane * 8]);
  }
  asm volatile("s_waitcnt vmcnt(0)" ::: "memory");
  __builtin_amdgcn_s_barrier();
  asm volatile("" ::: "memory");

  f32x4 o[2][6] = {};
  f32x4 eA[2], eB[2];

#define HALF(ET, PAR, DO_V, DO_PV) do {                                               \
    { /* stage K(kb+1) FIRST (drained at this round's barrier) */                     \
      size_t kidx = (size_t)(b * 256 + kb + 1);                                       \
      size_t kmax = (size_t)(b * 256 + 255);                                          \
      if (kidx > kmax) kidx = kmax;                                                   \
      const __bf16* srcK = KA + kidx * 12288;                                         \
      gload_lds16(srcK + hpK1 * 3072 + jK1 * 512 + lane * 8,                          \
                  &Kb_s[PAR ^ 1][hpK1 * 3072 + jK1 * 512 + lane * 8]);                \
      if (wid < 8)                                                                    \
        gload_lds16(srcK + hpK2 * 3072 + jK2 * 512 + lane * 8,                        \
                    &Kb_s[PAR ^ 1][hpK2 * 3072 + jK2 * 512 + lane * 8]);              \
    }                                                                                 \
    if (DO_V) { /* stage V second: stays in flight until the NEXT (odd) barrier */    \
      const __bf16* srcV = VA + (size_t)(b * 128 + (kb >> 1)) * 24576;                \
      _Pragma("unroll")                                                               \
      for (int tt = 0; tt < 3; ++tt) {                                                \
        int L = wid * 3 + tt;                                                         \
        int hpV = L / 12, jV = L - hpV * 12;                                          \
        gload_lds16(srcV + hpV * 6144 + jV * 512 + lane * 8,                          \
                    &Vb_s[hpV * 6144 + jV * 512 + lane * 8]);                         \
      }                                                                               \
    }                                                                                 \
    ET[0] = (f32x4){0.f, 0.f, 0.f, 0.f};                                              \
    ET[1] = (f32x4){0.f, 0.f, 0.f, 0.f};                                              \
    {                                                                                 \
      const __bf16* kbase = &Kb_s[PAR][hp * 3072 + lane * 8];                         \
      __builtin_amdgcn_s_setprio(1);                                                  \
      _Pragma("unroll")                                                               \
      for (int hh = 0; hh < 2; ++hh)                                                  \
        _Pragma("unroll")                                                             \
        for (int dc = 0; dc < 3; ++dc) {                                              \
          bf16x8 kf = *(const bf16x8*)(kbase + (hh * 3 + dc) * 512);                  \
          ET[hh] = __builtin_amdgcn_mfma_f32_16x16x32_bf16(kf, qf[hh][dc], ET[hh],    \
                                                           0, 0, 0);                  \
        }                                                                             \
      __builtin_amdgcn_s_setprio(0);                                                  \
    }                                                                                 \
    _Pragma("unroll")                                                                 \
    for (int rr = 0; rr < 4; ++rr) {                                                  \
      float e0 = __builtin_amdgcn_exp2f(ET[0][rr]);                                   \
      float e1 = __builtin_amdgcn_exp2f(ET[1][rr]);                                   \
      ET[0][rr] = e0;                                                                 \
      ET[1][rr] = e1;                                                                 \
      ps_s[PAR][qs * 1088 + (lg * 4 + rr) * 68 + hp * 17 + lr] = e0 + e1;             \
    }                                                                                 \
    if (DO_V) {                                                                       \
      asm volatile("s_waitcnt vmcnt(3) lgkmcnt(0)" ::: "memory");                     \
    } else {                                                                          \
      asm volatile("s_waitcnt vmcnt(0) lgkmcnt(0)" ::: "memory");                     \
    }                                                                                 \
    __builtin_amdgcn_s_barrier();                                                     \
    asm volatile("" ::: "memory");                                                    \
    {                                                                                 \
      float inv_[4];                                                                  \
      _Pragma("unroll")                                                               \
      for (int rr = 0; rr < 4; ++rr) {                                                \
        const int base = qs * 1088 + (lg * 4 + rr) * 68 + lr;                         \
        float tot = (ps_s[PAR][base] + ps_s[PAR][base + 17]) +                        \
                    (ps_s[PAR][base + 34] + ps_s[PAR][base + 51]);                    \
        inv_[rr] = 0.03608439182435161f * __builtin_amdgcn_rcpf(tot);                 \
      }                                                                               \
      _Pragma("unroll")                                                               \
      for (int rr = 0; rr < 4; ++rr) {                                                \
        ET[0][rr] *= inv_[rr];                                                        \
        ET[1][rr] *= inv_[rr];                                                        \
      }                                                                               \
    }                                                                                 \
    if (DO_PV) {                                                                      \
      bf16x8 pf0, pf1;                                                                \
      _Pragma("unroll")                                                               \
      for (int e2 = 0; e2 < 8; ++e2) {                                                \
        int rr = e2 & 3;                                                              \
        if (e2 < 4) { pf0[e2] = (__bf16)eA[0][rr]; pf1[e2] = (__bf16)eA[1][rr]; }     \
        else        { pf0[e2] = (__bf16)eB[0][rr]; pf1[e2] = (__bf16)eB[1][rr]; }     \
      }                                                                               \
      const __bf16* vbase = &Vb_s[hp * 6144 + lane * 8];                              \
      __builtin_amdgcn_s_setprio(1);                                                  \
      _Pragma("unroll")                                                               \
      for (int db = 0; db < 6; ++db) {                                                \
        bf16x8 vf0 = *(const bf16x8*)(vbase + db * 512);                              \
        bf16x8 vf1 = *(const bf16x8*)(vbase + (6 + db) * 512);                        \
        o[0][db] = __builtin_amdgcn_mfma_f32_16x16x32_bf16(pf0, vf0, o[0][db], 0, 0, 0); \
        o[1][db] = __builtin_amdgcn_mfma_f32_16x16x32_bf16(pf1, vf1, o[1][db], 0, 0, 0); \
      }                                                                               \
      __builtin_amdgcn_s_setprio(0);                                                  \
    }                                                                                 \
    ++kb;                                                                             \
  } while (0)

  for (int rp = 0; rp < 128; rp += 2) {
    HALF(eA, 0, 1, 0);
    HALF(eB, 1, 0, 1);
  }
#undef HALF

#pragma unroll
  for (int hh = 0; hh < 2; ++hh)
#pragma unroll
    for (int db = 0; db < 6; ++db)
#pragma unroll
      for (int rr = 0; rr < 4; ++rr)
        attn2[(size_t)(b * 4096 + q0 + lg * 4 + rr) * 1536 + ks * 768 +
              (hp * 2 + hh) * 96 + db * 16 + lr] = (__bf16)o[hh][db][rr];
}

// ---------------- reduce 2 k-split slices -> bf16 ----------------
__global__ __launch_bounds__(256) void k_reduce_attn(const __bf16* __restrict__ attn2,
                                                     __bf16* __restrict__ out) {
  int g = blockIdx.x * 256 + threadIdx.x;  // chunk of 8, total 8192*96
  int row = g / 96, c8 = g % 96;
  const __bf16* p = attn2 + (size_t)row * 1536 + c8 * 8;
  bf16x8 v0 = *(const bf16x8*)(p);
  bf16x8 v1 = *(const bf16x8*)(p + 768);
  bf16x8 r;
#pragma unroll
  for (int e = 0; e < 8; ++e) r[e] = (__bf16)((float)v0[e] + (float)v1[e]);
  *(bf16x8*)(out + (size_t)row * 768 + c8 * 8) = r;
}

// ---------------- launcher ----------------
extern "C" void kernel_launch(void* const* d_in, const int* in_sizes, int n_in,
                              void* d_out, int out_size, void* d_ws, size_t ws_size,
                              hipStream_t stream) {
  (void)in_sizes; (void)n_in; (void)out_size; (void)ws_size;
  const float* x     = (const float*)d_in[0];
  const float* ln1_g = (const float*)d_in[1];
  const float* ln1_b = (const float*)d_in[2];
  const float* wq    = (const float*)d_in[3];
  const float* bq    = (const float*)d_in[4];
  const float* wk    = (const float*)d_in[5];
  const float* bk    = (const float*)d_in[6];
  const float* wv    = (const float*)d_in[7];
  const float* bv    = (const float*)d_in[8];
  const float* wp    = (const float*)d_in[9];
  const float* bp    = (const float*)d_in[10];
  const float* ln2_g = (const float*)d_in[11];
  const float* ln2_b = (const float*)d_in[12];
  const float* w1    = (const float*)d_in[13];
  const float* b1    = (const float*)d_in[14];
  const float* w2    = (const float*)d_in[15];
  const float* b2    = (const float*)d_in[16];

  char* ws = (char*)d_ws;
  const size_t o_wqkvT = 0;                                   // [2304][768] bf16
  const size_t o_wpT   = o_wqkvT + (size_t)2304 * 768 * 2;    // [768][768] bf16
  const size_t o_w1T   = o_wpT   + (size_t)768 * 768 * 2;     // [3072][768] bf16
  const size_t o_w2T   = o_w1T   + (size_t)768 * 3072 * 2;    // [768][3072] bf16
  const size_t o_bqkv  = o_w2T   + (size_t)3072 * 768 * 2;    // [2304] f32
  const size_t o_xn    = o_bqkv  + (size_t)2304 * 4;          // [8192][768] bf16
  const size_t o_qkv   = o_xn    + (size_t)8192 * 768 * 2;    // [8192][2304] bf16
  const size_t o_KA    = o_qkv   + (size_t)8192 * 2304 * 2;   // [2][256][1536][8] bf16
  const size_t o_VA    = o_KA    + (size_t)2 * 256 * 1536 * 8 * 2;
  const size_t o_attn2 = o_VA    + (size_t)2 * 128 * 3072 * 8 * 2;  // [8192][1536] bf16
  // aliases (lifetime-disjoint):
  const size_t o_x1      = o_attn2;                               // [8192][768] f32
  const size_t o_part    = o_attn2 + (size_t)8192 * 768 * 4;      // [2][8192][768] bf16
  const size_t o_attnred = o_KA;     // [8192][768] bf16 (KA dead after attention)
  const size_t o_xn2     = o_VA;     // [8192][768] bf16 (VA dead after attention)
  const size_t o_hmid    = o_xn;     // [8192][3072] bf16 (spans xn+qkv, both dead)

  __bf16* wqkvT = (__bf16*)(ws + o_wqkvT);
  __bf16* wpT   = (__bf16*)(ws + o_wpT);
  __bf16* w1T   = (__bf16*)(ws + o_w1T);
  __bf16* w2T   = (__bf16*)(ws + o_w2T);
  float*  bqkv  = (float*)(ws + o_bqkv);
  __bf16* xn    = (__bf16*)(ws + o_xn);
  __bf16* qkvb  = (__bf16*)(ws + o_qkv);
  __bf16* KA    = (__bf16*)(ws + o_KA);
  __bf16* VA    = (__bf16*)(ws + o_VA);
  __bf16* attn2 = (__bf16*)(ws + o_attn2);
  float*  x1    = (float*)(ws + o_x1);
  __bf16* part  = (__bf16*)(ws + o_part);
  __bf16* attnr = (__bf16*)(ws + o_attnred);
  __bf16* xn2   = (__bf16*)(ws + o_xn2);
  __bf16* hmid  = (__bf16*)(ws + o_hmid);

  dim3 tb(32, 8);
  // all four 768x768 transposes in one launch
  k_transpose_w4<<<dim3(24, 24, 4), tb, 0, stream>>>(wq, wk, wv, wp,
                                                     wqkvT, wqkvT + (size_t)768 * 768,
                                                     wqkvT + (size_t)2 * 768 * 768, wpT);
  k_transpose_w<<<dim3(96, 24), tb, 0, stream>>>(w1, w1T, 768, 3072, 768, 0);
  k_transpose_w<<<dim3(24, 96), tb, 0, stream>>>(w2, w2T, 3072, 768, 3072, 0);
  k_pack_bias<<<9, 256, 0, stream>>>(bq, bk, bv, bqkv);

  // LN1 -> xn
  k_layernorm<<<2048, 256, 0, stream>>>(x, ln1_g, ln1_b, xn);
  // QKV projection (fused q|k|v; Q cols pre-scaled by log2e)
  k_gemm<0><<<1152, 256, 0, stream>>>(xn, wqkvT, bqkv, nullptr, qkvb, 8192, 2304, 768, 768, 768);
  // merged K/V fragment packing
  k_pack_kv<<<dim3(128, 2), 256, 0, stream>>>(qkvb, KA, VA);
  // attention: 256 blocks x 16 waves (1 block/CU, single machine-round)
  k_attn<<<256, 1024, 0, stream>>>(qkvb, KA, VA, attn2);
  // sum 2 k-split slices
  k_reduce_attn<<<3072, 256, 0, stream>>>(attn2, attnr);
  // output projection + residual -> x1 (f32)
  k_gemm<1><<<384, 256, 0, stream>>>(attnr, wpT, bp, x, x1, 8192, 768, 768, 768, 768);
  // LN2 -> xn2
  k_layernorm<<<2048, 256, 0, stream>>>(x1, ln2_g, ln2_b, xn2);
  // MLP1 + tanh-GELU -> hmid
  k_gemm<2><<<1536, 256, 0, stream>>>(xn2, w1T, b1, nullptr, hmid, 8192, 3072, 768, 768, 768);
  // MLP2 split-K=2 (concurrent halves -> bf16 partials), then fuse
  k_gemm<3><<<dim3(384, 2), 256, 0, stream>>>(hmid, w2T, nullptr, nullptr, part,
                                              8192, 768, 1536, 3072, 3072);
  k_fuse_mlp2<<<3072, 256, 0, stream>>>(part, part + (size_t)8192 * 768, b2, x1,
                                        (float*)d_out);
}

// Round 12
// 435.103 us; speedup vs baseline: 1.2417x; 1.0249x over previous
//
#include <hip/hip_runtime.h>
#include <cstdint>
#include <cstddef>

#define AS1 __attribute__((address_space(1)))
#define AS3 __attribute__((address_space(3)))

typedef __attribute__((ext_vector_type(8))) __bf16 bf16x8;
typedef __attribute__((ext_vector_type(4))) __bf16 bf16x4;
typedef __attribute__((ext_vector_type(4))) float f32x4;

__device__ __forceinline__ void gload_lds16(const void* g, void* l) {
  __builtin_amdgcn_global_load_lds((AS1 void*)g, (AS3 void*)l, 16, 0, 0);
}

// ---------------- merged prologue: 6 weight transposes + bias pack + LN1 ----------------
// blocks [0,2304): four 768x768 transposes (wq,wk,wv->wqkvT, wp->wpT)
// blocks [2304,4608): w1 [768][3072] -> w1T [3072][768]
// blocks [4608,6912): w2 [3072][768] -> w2T [768][3072]
// blocks [6912,6921): qkv bias pack
// blocks [6921,8969): LayerNorm1 (4 rows per block)
__global__ __launch_bounds__(256) void k_prep(
    const float* __restrict__ wq, const float* __restrict__ wk,
    const float* __restrict__ wv, const float* __restrict__ wp,
    const float* __restrict__ w1, const float* __restrict__ w2,
    const float* __restrict__ bq, const float* __restrict__ bk,
    const float* __restrict__ bv,
    const float* __restrict__ x, const float* __restrict__ ln1_g,
    const float* __restrict__ ln1_b,
    __bf16* __restrict__ wqkvT, __bf16* __restrict__ wpT,
    __bf16* __restrict__ w1T, __bf16* __restrict__ w2T,
    float* __restrict__ bqkv, __bf16* __restrict__ xn) {
  __shared__ float tile[32][33];
  const int bid = blockIdx.x;
  const int t = threadIdx.x;
  const int tx = t & 31, ty = t >> 5;

  if (bid < 2304) {  // 4x 768x768 transpose
    const int which = bid / 576, r = bid % 576;
    const float* src = which == 0 ? wq : which == 1 ? wk : which == 2 ? wv : wp;
    __bf16* dst = which == 3 ? wpT : wqkvT + (size_t)which * 768 * 768;
    const int bx = (r % 24) * 32, by = (r / 24) * 32;
#pragma unroll
    for (int ii = 0; ii < 4; ++ii) {
      int i = ty + ii * 8;
      tile[i][tx] = src[(size_t)(by + i) * 768 + bx + tx];
    }
    __syncthreads();
#pragma unroll
    for (int ii = 0; ii < 4; ++ii) {
      int i = ty + ii * 8;
      dst[(size_t)(bx + i) * 768 + by + tx] = (__bf16)tile[tx][i];
    }
  } else if (bid < 4608) {  // w1T[3072][768] = w1[768][3072]^T
    const int r = bid - 2304;
    const int bx = (r % 96) * 32, by = (r / 96) * 32;
#pragma unroll
    for (int ii = 0; ii < 4; ++ii) {
      int i = ty + ii * 8;
      tile[i][tx] = w1[(size_t)(by + i) * 3072 + bx + tx];
    }
    __syncthreads();
#pragma unroll
    for (int ii = 0; ii < 4; ++ii) {
      int i = ty + ii * 8;
      w1T[(size_t)(bx + i) * 768 + by + tx] = (__bf16)tile[tx][i];
    }
  } else if (bid < 6912) {  // w2T[768][3072] = w2[3072][768]^T
    const int r = bid - 4608;
    const int bx = (r % 24) * 32, by = (r / 24) * 32;
#pragma unroll
    for (int ii = 0; ii < 4; ++ii) {
      int i = ty + ii * 8;
      tile[i][tx] = w2[(size_t)(by + i) * 768 + bx + tx];
    }
    __syncthreads();
#pragma unroll
    for (int ii = 0; ii < 4; ++ii) {
      int i = ty + ii * 8;
      w2T[(size_t)(bx + i) * 3072 + by + tx] = (__bf16)tile[tx][i];
    }
  } else if (bid < 6921) {  // bias pack
    int i = (bid - 6912) * 256 + t;
    if (i < 768) bqkv[i] = bq[i];
    else if (i < 1536) bqkv[i] = bk[i - 768];
    else if (i < 2304) bqkv[i] = bv[i - 1536];
  } else {  // LN1: f32 in -> bf16 out
    const int row = (bid - 6921) * 4 + (t >> 6);
    const int lane = t & 63;
    const float* xr = x + (size_t)row * 768;
    float4 v[3];
#pragma unroll
    for (int j = 0; j < 3; ++j) v[j] = *(const float4*)(xr + j * 256 + lane * 4);
    float s = 0.f, ss = 0.f;
#pragma unroll
    for (int j = 0; j < 3; ++j) {
      s += v[j].x + v[j].y + v[j].z + v[j].w;
      ss += v[j].x * v[j].x + v[j].y * v[j].y + v[j].z * v[j].z + v[j].w * v[j].w;
    }
#pragma unroll
    for (int off = 32; off > 0; off >>= 1) {
      s += __shfl_xor(s, off);
      ss += __shfl_xor(ss, off);
    }
    const float mu = s * (1.f / 768.f);
    const float rstd = rsqrtf(ss * (1.f / 768.f) - mu * mu + 1e-5f);
    __bf16* orow = xn + (size_t)row * 768;
#pragma unroll
    for (int j = 0; j < 3; ++j) {
      float4 gg = *(const float4*)(ln1_g + j * 256 + lane * 4);
      float4 bb = *(const float4*)(ln1_b + j * 256 + lane * 4);
      const int base = j * 256 + lane * 4;
      orow[base + 0] = (__bf16)((v[j].x - mu) * rstd * gg.x + bb.x);
      orow[base + 1] = (__bf16)((v[j].y - mu) * rstd * gg.y + bb.y);
      orow[base + 2] = (__bf16)((v[j].z - mu) * rstd * gg.z + bb.z);
      orow[base + 3] = (__bf16)((v[j].w - mu) * rstd * gg.w + bb.w);
    }
  }
}

// ---------------- LayerNorm, bf16 input -> bf16 output (LN2 on bf16 trunk) ----------------
__global__ __launch_bounds__(256) void k_layernorm_b(const __bf16* __restrict__ x,
                                                     const float* __restrict__ g,
                                                     const float* __restrict__ b,
                                                     __bf16* __restrict__ out) {
  const int row = blockIdx.x * 4 + (threadIdx.x >> 6);
  const int lane = threadIdx.x & 63;
  const __bf16* xr = x + (size_t)row * 768;
  float v[12];
#pragma unroll
  for (int j = 0; j < 3; ++j) {
    bf16x4 u = *(const bf16x4*)(xr + j * 256 + lane * 4);
#pragma unroll
    for (int e = 0; e < 4; ++e) v[j * 4 + e] = (float)u[e];
  }
  float s = 0.f, ss = 0.f;
#pragma unroll
  for (int j = 0; j < 12; ++j) {
    s += v[j];
    ss += v[j] * v[j];
  }
#pragma unroll
  for (int off = 32; off > 0; off >>= 1) {
    s += __shfl_xor(s, off);
    ss += __shfl_xor(ss, off);
  }
  const float mu = s * (1.f / 768.f);
  const float rstd = rsqrtf(ss * (1.f / 768.f) - mu * mu + 1e-5f);
  __bf16* orow = out + (size_t)row * 768;
#pragma unroll
  for (int j = 0; j < 3; ++j) {
    float4 gg = *(const float4*)(g + j * 256 + lane * 4);
    float4 bb = *(const float4*)(b + j * 256 + lane * 4);
    const int base = j * 256 + lane * 4;
    orow[base + 0] = (__bf16)((v[j * 4 + 0] - mu) * rstd * gg.x + bb.x);
    orow[base + 1] = (__bf16)((v[j * 4 + 1] - mu) * rstd * gg.y + bb.y);
    orow[base + 2] = (__bf16)((v[j * 4 + 2] - mu) * rstd * gg.z + bb.z);
    orow[base + 3] = (__bf16)((v[j * 4 + 3] - mu) * rstd * gg.w + bb.w);
  }
}

// ---------------- GEMM: C[M][N] = A[M][K(lda)] * BT[N][K(ldb)]^T (+epilogue) ----------------
// 1-D grid, XCD-aware remap: xcd = bid&7 owns a contiguous band of row-groups.
// MODE 0: +bias, store bf16; cols<768 (Q) pre-scaled by log2(e)
// MODE 1: +bias+resid(f32), store bf16 (residual trunk)
// MODE 2: +bias, tanh-GELU, store bf16
// MODE 3: split-K half (blockIdx.y = k-half); raw partial, store bf16 at half offset
template <int MODE>
__global__ __launch_bounds__(256) void k_gemm(const __bf16* __restrict__ A,
                                              const __bf16* __restrict__ BT,
                                              const float* __restrict__ bias,
                                              const float* __restrict__ resid,
                                              void* __restrict__ Cout,
                                              int M, int N, int K, int lda, int ldb) {
  __shared__ __bf16 As[128 * 32];
  __shared__ __bf16 Bs[128 * 32];
  const int nx = N >> 7;
  const int rpx = (M >> 7) >> 3;  // row-groups per XCD
  const int xcd = blockIdx.x & 7;
  const int ib = blockIdx.x >> 3;
  const int n0 = (ib % nx) << 7;
  const int m0 = (xcd * rpx + ib / nx) << 7;
  if constexpr (MODE == 3) {
    A += (size_t)blockIdx.y * K;
    BT += (size_t)blockIdx.y * K;
  }
  const int tid = threadIdx.x;
  const int wid = tid >> 6, lane = tid & 63;
  const int wm = wid >> 1, wn = wid & 1;
  const int lr = lane & 15, lg = lane >> 4;

  f32x4 acc[4][4] = {};

  for (int k0 = 0; k0 < K; k0 += 32) {
#pragma unroll
    for (int it = 0; it < 2; ++it) {
      int t = tid + it * 256;
      int r = t >> 2, c = (t & 3) * 8;
      gload_lds16(A + (size_t)(m0 + r) * lda + k0 + c, As + t * 8);
      gload_lds16(BT + (size_t)(n0 + r) * ldb + k0 + c, Bs + t * 8);
    }
    __syncthreads();
    bf16x8 af[4], bf[4];
#pragma unroll
    for (int i = 0; i < 4; ++i) af[i] = *(const bf16x8*)(As + (wm * 64 + i * 16 + lr) * 32 + lg * 8);
#pragma unroll
    for (int j = 0; j < 4; ++j) bf[j] = *(const bf16x8*)(Bs + (wn * 64 + j * 16 + lr) * 32 + lg * 8);
#pragma unroll
    for (int i = 0; i < 4; ++i)
#pragma unroll
      for (int j = 0; j < 4; ++j)
        acc[i][j] = __builtin_amdgcn_mfma_f32_16x16x32_bf16(af[i], bf[j], acc[i][j], 0, 0, 0);
    __syncthreads();
  }

#pragma unroll
  for (int i = 0; i < 4; ++i)
#pragma unroll
    for (int j = 0; j < 4; ++j)
#pragma unroll
      for (int r = 0; r < 4; ++r) {
        int row = m0 + wm * 64 + i * 16 + lg * 4 + r;
        int col = n0 + wn * 64 + j * 16 + lr;
        float v = acc[i][j][r];
        if constexpr (MODE != 3) v += bias[col];
        size_t idx = (size_t)row * N + col;
        if constexpr (MODE == 0) {
          if (col < 768) v *= 1.44269504088896f;  // Q pre-scale: exp(x) = 2^(x*log2e)
          ((__bf16*)Cout)[idx] = (__bf16)v;
        } else if constexpr (MODE == 1) {
          ((__bf16*)Cout)[idx] = (__bf16)(v + resid[idx]);
        } else if constexpr (MODE == 2) {
          float u = 0.7978845608f * (v + 0.044715f * v * v * v);
          float t = __builtin_amdgcn_exp2f(u * 2.88539008f);  // e^{2u}
          float th = 1.f - 2.f * __builtin_amdgcn_rcpf(t + 1.f);
          ((__bf16*)Cout)[idx] = (__bf16)(0.5f * v * (1.f + th));
        } else {
          ((__bf16*)Cout)[(size_t)blockIdx.y * M * N + idx] = (__bf16)v;
        }
      }
}

// ---------------- fuse MLP2 split-K partials: out = p0+p1+bias+resid(bf16) -> f32 ----------
__global__ __launch_bounds__(256) void k_fuse_mlp2(const __bf16* __restrict__ p0,
                                                   const __bf16* __restrict__ p1,
                                                   const float* __restrict__ bias,
                                                   const __bf16* __restrict__ resid,
                                                   float* __restrict__ out) {
  int g = blockIdx.x * 256 + threadIdx.x;
  int base = g * 8;
  int col = base % 768;
  bf16x8 a = *(const bf16x8*)(p0 + base);
  bf16x8 b = *(const bf16x8*)(p1 + base);
  bf16x8 rr = *(const bf16x8*)(resid + base);
  float4 b0 = *(const float4*)(bias + col);
  float4 b1 = *(const float4*)(bias + col + 4);
  float4 o0, o1;
  o0.x = (float)rr[0] + b0.x + (float)a[0] + (float)b[0];
  o0.y = (float)rr[1] + b0.y + (float)a[1] + (float)b[1];
  o0.z = (float)rr[2] + b0.z + (float)a[2] + (float)b[2];
  o0.w = (float)rr[3] + b0.w + (float)a[3] + (float)b[3];
  o1.x = (float)rr[4] + b1.x + (float)a[4] + (float)b[4];
  o1.y = (float)rr[5] + b1.y + (float)a[5] + (float)b[5];
  o1.z = (float)rr[6] + b1.z + (float)a[6] + (float)b[6];
  o1.w = (float)rr[7] + b1.w + (float)a[7] + (float)b[7];
  *(float4*)(out + base) = o0;
  *(float4*)(out + base + 4) = o1;
}

// ---------------- merged K/V pack (per 32-row group g): KA granules 2g,2g+1 + VA group g ----
// KA16[b][kb16][hp][hh][dc][lane][8] = K[b][kb*16 + (lane&15)][hp*192+hh*96+dc*32+(lane>>4)*8+e]
// VA32[b][g][hp][hh][db][lane][e]   = V[b][g*32 + kappa(lane>>4,e)][hp*192+hh*96+db*16+(lane&15)]
// kappa(lg,e) = (e>>2)*16 + lg*4 + (e&3)
__global__ __launch_bounds__(256) void k_pack_kv(const __bf16* __restrict__ qkv,
                                                 __bf16* __restrict__ KA,
                                                 __bf16* __restrict__ VA) {
  __shared__ __bf16 vtile[32][772];
  const int g = blockIdx.x, b = blockIdx.y;  // g in [0,128)
  const int t = threadIdx.x;
#pragma unroll
  for (int half = 0; half < 2; ++half) {
    int kb = g * 2 + half;
#pragma unroll
    for (int i = 0; i < 6; ++i) {
      int c = t + i * 256;  // [0,1536)
      int lane = c & 63, f = c >> 6;
      int dc = f % 3, hh = (f / 3) & 1, hp = f / 6;
      int row = kb * 16 + (lane & 15);
      int col = 768 + hp * 192 + hh * 96 + dc * 32 + (lane >> 4) * 8;
      bf16x8 v = *(const bf16x8*)(qkv + (size_t)(b * 4096 + row) * 2304 + col);
      *(bf16x8*)(KA + ((size_t)(b * 256 + kb) * 1536 + c) * 8) = v;
    }
  }
#pragma unroll
  for (int i = 0; i < 12; ++i) {
    int c = t + i * 256;
    int row = c / 96, c8 = c % 96;
    *(bf16x8*)(&vtile[row][c8 * 8]) =
        *(const bf16x8*)(qkv + (size_t)(b * 4096 + g * 32 + row) * 2304 + 1536 + c8 * 8);
  }
  __syncthreads();
#pragma unroll
  for (int i = 0; i < 12; ++i) {
    int c = t + i * 256;  // [0,3072)
    int lane = c & 63, f = c >> 6;
    int db = f % 6, hh = (f / 6) & 1, hp = f / 12;
    int d = hp * 192 + hh * 96 + db * 16 + (lane & 15);
    int lg_ = lane >> 4;
    bf16x8 v;
#pragma unroll
    for (int e = 0; e < 8; ++e) {
      int krow = (e >> 2) * 16 + lg_ * 4 + (e & 3);
      v[e] = vtile[krow][d];
    }
    *(bf16x8*)(VA + ((size_t)(b * 128 + g) * 3072 + c) * 8) = v;
  }
}

// ---------------- fused attention v10: ks=2, 256 blocks (1/CU), LDS-shared K/V ----------------
__global__ __launch_bounds__(1024, 4) void k_attn(const __bf16* __restrict__ qkv,
                                                  const __bf16* __restrict__ KA,
                                                  const __bf16* __restrict__ VA,
                                                  __bf16* __restrict__ attn2) {
  __shared__ __bf16 Kb_s[2][12288];
  __shared__ __bf16 Vb_s[24576];
  __shared__ float ps_s[2][4352];
  const int bid = blockIdx.x;
  const int slice = bid & 3;
  const int b = slice >> 1, ks = slice & 1;
  const int qb = bid >> 2;
  const int wid = threadIdx.x >> 6;
  const int qs = wid & 3, hp = wid >> 2;
  const int q0 = qb * 64 + qs * 16;
  const int lane = threadIdx.x & 63;
  const int lr = lane & 15, lg = lane >> 4;

  const __bf16* Qb = qkv + (size_t)(b * 4096 + q0) * 2304;
  bf16x8 qf[2][3];
#pragma unroll
  for (int hh = 0; hh < 2; ++hh)
#pragma unroll
    for (int dc = 0; dc < 3; ++dc)
      qf[hh][dc] = *(const bf16x8*)(Qb + (size_t)lr * 2304 + (hp * 2 + hh) * 96 + dc * 32 + lg * 8);

  const int L1 = wid, hpK1 = L1 / 6, jK1 = L1 - hpK1 * 6;
  const int L2 = wid + 16, hpK2 = L2 / 6, jK2 = L2 - hpK2 * 6;

  int kb = ks * 128;
  {
    const __bf16* srcK = KA + (size_t)(b * 256 + kb) * 12288;
    gload_lds16(srcK + hpK1 * 3072 + jK1 * 512 + lane * 8,
                &Kb_s[0][hpK1 * 3072 + jK1 * 512 + lane * 8]);
    if (wid < 8)
      gload_lds16(srcK + hpK2 * 3072 + jK2 * 512 + lane * 8,
                  &Kb_s[0][hpK2 * 3072 + jK2 * 512 + lane * 8]);
  }
  asm volatile("s_waitcnt vmcnt(0)" ::: "memory");
  __builtin_amdgcn_s_barrier();
  asm volatile("" ::: "memory");

  f32x4 o[2][6] = {};
  f32x4 eA[2], eB[2];

#define HALF(ET, PAR, DO_V, DO_PV) do {                                               \
    { /* stage K(kb+1) FIRST (drained at this round's barrier) */                     \
      size_t kidx = (size_t)(b * 256 + kb + 1);                                       \
      size_t kmax = (size_t)(b * 256 + 255);                                          \
      if (kidx > kmax) kidx = kmax;                                                   \
      const __bf16* srcK = KA + kidx * 12288;                                         \
      gload_lds16(srcK + hpK1 * 3072 + jK1 * 512 + lane * 8,                          \
                  &Kb_s[PAR ^ 1][hpK1 * 3072 + jK1 * 512 + lane * 8]);                \
      if (wid < 8)                                                                    \
        gload_lds16(srcK + hpK2 * 3072 + jK2 * 512 + lane * 8,                        \
                    &Kb_s[PAR ^ 1][hpK2 * 3072 + jK2 * 512 + lane * 8]);              \
    }                                                                                 \
    if (DO_V) { /* stage V second: stays in flight until the NEXT (odd) barrier */    \
      const __bf16* srcV = VA + (size_t)(b * 128 + (kb >> 1)) * 24576;                \
      _Pragma("unroll")                                                               \
      for (int tt = 0; tt < 3; ++tt) {                                                \
        int L = wid * 3 + tt;                                                         \
        int hpV = L / 12, jV = L - hpV * 12;                                          \
        gload_lds16(srcV + hpV * 6144 + jV * 512 + lane * 8,                          \
                    &Vb_s[hpV * 6144 + jV * 512 + lane * 8]);                         \
      }                                                                               \
    }                                                                                 \
    ET[0] = (f32x4){0.f, 0.f, 0.f, 0.f};                                              \
    ET[1] = (f32x4){0.f, 0.f, 0.f, 0.f};                                              \
    {                                                                                 \
      const __bf16* kbase = &Kb_s[PAR][hp * 3072 + lane * 8];                         \
      __builtin_amdgcn_s_setprio(1);                                                  \
      _Pragma("unroll")                                                               \
      for (int hh = 0; hh < 2; ++hh)                                                  \
        _Pragma("unroll")                                                             \
        for (int dc = 0; dc < 3; ++dc) {                                              \
          bf16x8 kf = *(const bf16x8*)(kbase + (hh * 3 + dc) * 512);                  \
          ET[hh] = __builtin_amdgcn_mfma_f32_16x16x32_bf16(kf, qf[hh][dc], ET[hh],    \
                                                           0, 0, 0);                  \
        }                                                                             \
      __builtin_amdgcn_s_setprio(0);                                                  \
    }                                                                                 \
    _Pragma("unroll")                                                                 \
    for (int rr = 0; rr < 4; ++rr) {                                                  \
      float e0 = __builtin_amdgcn_exp2f(ET[0][rr]);                                   \
      float e1 = __builtin_amdgcn_exp2f(ET[1][rr]);                                   \
      ET[0][rr] = e0;                                                                 \
      ET[1][rr] = e1;                                                                 \
      ps_s[PAR][qs * 1088 + (lg * 4 + rr) * 68 + hp * 17 + lr] = e0 + e1;             \
    }                                                                                 \
    if (DO_V) {                                                                       \
      asm volatile("s_waitcnt vmcnt(3) lgkmcnt(0)" ::: "memory");                     \
    } else {                                                                          \
      asm volatile("s_waitcnt vmcnt(0) lgkmcnt(0)" ::: "memory");                     \
    }                                                                                 \
    __builtin_amdgcn_s_barrier();                                                     \
    asm volatile("" ::: "memory");                                                    \
    {                                                                                 \
      float inv_[4];                                                                  \
      _Pragma("unroll")                                                               \
      for (int rr = 0; rr < 4; ++rr) {                                                \
        const int base = qs * 1088 + (lg * 4 + rr) * 68 + lr;                         \
        float tot = (ps_s[PAR][base] + ps_s[PAR][base + 17]) +                        \
                    (ps_s[PAR][base + 34] + ps_s[PAR][base + 51]);                    \
        inv_[rr] = 0.03608439182435161f * __builtin_amdgcn_rcpf(tot);                 \
      }                                                                               \
      _Pragma("unroll")                                                               \
      for (int rr = 0; rr < 4; ++rr) {                                                \
        ET[0][rr] *= inv_[rr];                                                        \
        ET[1][rr] *= inv_[rr];                                                        \
      }                                                                               \
    }                                                                                 \
    if (DO_PV) {                                                                      \
      bf16x8 pf0, pf1;                                                                \
      _Pragma("unroll")                                                               \
      for (int e2 = 0; e2 < 8; ++e2) {                                                \
        int rr = e2 & 3;                                                              \
        if (e2 < 4) { pf0[e2] = (__bf16)eA[0][rr]; pf1[e2] = (__bf16)eA[1][rr]; }     \
        else        { pf0[e2] = (__bf16)eB[0][rr]; pf1[e2] = (__bf16)eB[1][rr]; }     \
      }                                                                               \
      const __bf16* vbase = &Vb_s[hp * 6144 + lane * 8];                              \
      __builtin_amdgcn_s_setprio(1);                                                  \
      _Pragma("unroll")                                                               \
      for (int db = 0; db < 6; ++db) {                                                \
        bf16x8 vf0 = *(const bf16x8*)(vbase + db * 512);                              \
        bf16x8 vf1 = *(const bf16x8*)(vbase + (6 + db) * 512);                        \
        o[0][db] = __builtin_amdgcn_mfma_f32_16x16x32_bf16(pf0, vf0, o[0][db], 0, 0, 0); \
        o[1][db] = __builtin_amdgcn_mfma_f32_16x16x32_bf16(pf1, vf1, o[1][db], 0, 0, 0); \
      }                                                                               \
      __builtin_amdgcn_s_setprio(0);                                                  \
    }                                                                                 \
    ++kb;                                                                             \
  } while (0)

  for (int rp = 0; rp < 128; rp += 2) {
    HALF(eA, 0, 1, 0);
    HALF(eB, 1, 0, 1);
  }
#undef HALF

#pragma unroll
  for (int hh = 0; hh < 2; ++hh)
#pragma unroll
    for (int db = 0; db < 6; ++db)
#pragma unroll
      for (int rr = 0; rr < 4; ++rr)
        attn2[(size_t)(b * 4096 + q0 + lg * 4 + rr) * 1536 + ks * 768 +
              (hp * 2 + hh) * 96 + db * 16 + lr] = (__bf16)o[hh][db][rr];
}

// ---------------- reduce 2 k-split slices -> bf16 ----------------
__global__ __launch_bounds__(256) void k_reduce_attn(const __bf16* __restrict__ attn2,
                                                     __bf16* __restrict__ out) {
  int g = blockIdx.x * 256 + threadIdx.x;
  int row = g / 96, c8 = g % 96;
  const __bf16* p = attn2 + (size_t)row * 1536 + c8 * 8;
  bf16x8 v0 = *(const bf16x8*)(p);
  bf16x8 v1 = *(const bf16x8*)(p + 768);
  bf16x8 r;
#pragma unroll
  for (int e = 0; e < 8; ++e) r[e] = (__bf16)((float)v0[e] + (float)v1[e]);
  *(bf16x8*)(out + (size_t)row * 768 + c8 * 8) = r;
}

// ---------------- launcher ----------------
extern "C" void kernel_launch(void* const* d_in, const int* in_sizes, int n_in,
                              void* d_out, int out_size, void* d_ws, size_t ws_size,
                              hipStream_t stream) {
  (void)in_sizes; (void)n_in; (void)out_size; (void)ws_size;
  const float* x     = (const float*)d_in[0];
  const float* ln1_g = (const float*)d_in[1];
  const float* ln1_b = (const float*)d_in[2];
  const float* wq    = (const float*)d_in[3];
  const float* bq    = (const float*)d_in[4];
  const float* wk    = (const float*)d_in[5];
  const float* bk    = (const float*)d_in[6];
  const float* wv    = (const float*)d_in[7];
  const float* bv    = (const float*)d_in[8];
  const float* wp    = (const float*)d_in[9];
  const float* bp    = (const float*)d_in[10];
  const float* ln2_g = (const float*)d_in[11];
  const float* ln2_b = (const float*)d_in[12];
  const float* w1    = (const float*)d_in[13];
  const float* b1    = (const float*)d_in[14];
  const float* w2    = (const float*)d_in[15];
  const float* b2    = (const float*)d_in[16];

  char* ws = (char*)d_ws;
  const size_t o_wqkvT = 0;                                   // [2304][768] bf16
  const size_t o_wpT   = o_wqkvT + (size_t)2304 * 768 * 2;    // [768][768] bf16
  const size_t o_w1T   = o_wpT   + (size_t)768 * 768 * 2;     // [3072][768] bf16
  const size_t o_w2T   = o_w1T   + (size_t)768 * 3072 * 2;    // [768][3072] bf16
  const size_t o_bqkv  = o_w2T   + (size_t)3072 * 768 * 2;    // [2304] f32
  const size_t o_xn    = o_bqkv  + (size_t)2304 * 4;          // [8192][768] bf16
  const size_t o_qkv   = o_xn    + (size_t)8192 * 768 * 2;    // [8192][2304] bf16
  const size_t o_KA    = o_qkv   + (size_t)8192 * 2304 * 2;   // [2][256][1536][8] bf16
  const size_t o_VA    = o_KA    + (size_t)2 * 256 * 1536 * 8 * 2;
  const size_t o_attn2 = o_VA    + (size_t)2 * 128 * 3072 * 8 * 2;  // [8192][1536] bf16
  // aliases (lifetime-disjoint):
  const size_t o_x1      = o_attn2;                               // [8192][768] bf16 trunk
  const size_t o_part    = o_attn2 + (size_t)8192 * 768 * 4;      // [2][8192][768] bf16
  const size_t o_attnred = o_KA;     // [8192][768] bf16 (KA dead after attention)
  const size_t o_xn2     = o_VA;     // [8192][768] bf16 (VA dead after attention)
  const size_t o_hmid    = o_xn;     // [8192][3072] bf16 (spans xn+qkv, both dead)

  __bf16* wqkvT = (__bf16*)(ws + o_wqkvT);
  __bf16* wpT   = (__bf16*)(ws + o_wpT);
  __bf16* w1T   = (__bf16*)(ws + o_w1T);
  __bf16* w2T   = (__bf16*)(ws + o_w2T);
  float*  bqkv  = (float*)(ws + o_bqkv);
  __bf16* xn    = (__bf16*)(ws + o_xn);
  __bf16* qkvb  = (__bf16*)(ws + o_qkv);
  __bf16* KA    = (__bf16*)(ws + o_KA);
  __bf16* VA    = (__bf16*)(ws + o_VA);
  __bf16* attn2 = (__bf16*)(ws + o_attn2);
  __bf16* x1b   = (__bf16*)(ws + o_x1);
  __bf16* part  = (__bf16*)(ws + o_part);
  __bf16* attnr = (__bf16*)(ws + o_attnred);
  __bf16* xn2   = (__bf16*)(ws + o_xn2);
  __bf16* hmid  = (__bf16*)(ws + o_hmid);

  // merged prologue: all weight transposes + bias pack + LN1 in one launch
  k_prep<<<8969, 256, 0, stream>>>(wq, wk, wv, wp, w1, w2, bq, bk, bv,
                                   x, ln1_g, ln1_b,
                                   wqkvT, wpT, w1T, w2T, bqkv, xn);
  // QKV projection (fused q|k|v; Q cols pre-scaled by log2e)
  k_gemm<0><<<1152, 256, 0, stream>>>(xn, wqkvT, bqkv, nullptr, qkvb, 8192, 2304, 768, 768, 768);
  // merged K/V fragment packing
  k_pack_kv<<<dim3(128, 2), 256, 0, stream>>>(qkvb, KA, VA);
  // attention: 256 blocks x 16 waves (1 block/CU, single machine-round)
  k_attn<<<256, 1024, 0, stream>>>(qkvb, KA, VA, attn2);
  // sum 2 k-split slices
  k_reduce_attn<<<3072, 256, 0, stream>>>(attn2, attnr);
  // output projection + residual -> x1b (bf16 trunk)
  k_gemm<1><<<384, 256, 0, stream>>>(attnr, wpT, bp, x, x1b, 8192, 768, 768, 768, 768);
  // LN2 (bf16 in) -> xn2
  k_layernorm_b<<<2048, 256, 0, stream>>>(x1b, ln2_g, ln2_b, xn2);
  // MLP1 + tanh-GELU -> hmid
  k_gemm<2><<<1536, 256, 0, stream>>>(xn2, w1T, b1, nullptr, hmid, 8192, 3072, 768, 768, 768);
  // MLP2 split-K=2 (concurrent halves -> bf16 partials), then fuse
  k_gemm<3><<<dim3(384, 2), 256, 0, stream>>>(hmid, w2T, nullptr, nullptr, part,
                                              8192, 768, 1536, 3072, 3072);
  k_fuse_mlp2<<<3072, 256, 0, stream>>>(part, part + (size_t)8192 * 768, b2, x1b,
                                        (float*)d_out);
}